// Round 1
// baseline (1188.819 us; speedup 1.0000x reference)
//
#include <hip/hip_runtime.h>
#include <hip/hip_bf16.h>

// Problem constants (fixed by the reference)
#define DIM 256
#define NH 8
#define DH 32
// GEMM tiling
#define BM 64
#define BN 64
#define BK 32

// ---------------------------------------------------------------------------
// Weight permutation: reference reshapes (N, DH, NH) so flat col c = d*NH + h.
// We store Q/K/V head-contiguous: c' = h*DH + d  ->  orig(c') = (c'%32)*8 + c'/32
// ---------------------------------------------------------------------------
__global__ void permute_w_cols(const float* __restrict__ W, float* __restrict__ Wp, float scale) {
    int idx = blockIdx.x * blockDim.x + threadIdx.x;   // 65536
    if (idx < DIM * DIM) {
        int k = idx >> 8, cp = idx & 255;
        int d = cp & 31, h = cp >> 5;
        int c = d * NH + h;
        Wp[idx] = W[k * DIM + c] * scale;
    }
}

__global__ void permute_w_rows(const float* __restrict__ W, float* __restrict__ Wp) {
    int idx = blockIdx.x * blockDim.x + threadIdx.x;   // 65536
    if (idx < DIM * DIM) {
        int kp = idx >> 8, j = idx & 255;
        int d = kp & 31, h = kp >> 5;
        int k = d * NH + h;
        Wp[idx] = W[k * DIM + j];
    }
}

__global__ void permute_bias(const float* __restrict__ b, float* __restrict__ bp, float scale) {
    int cp = threadIdx.x;
    int d = cp & 31, h = cp >> 5;
    bp[cp] = b[d * NH + h] * scale;
}

// ---------------------------------------------------------------------------
// fp32 SGEMM: C[M,256] = A[M,256] @ B[256,256] + bias   (row-major)
// 64x64 tile, BK=32, 256 threads, 4x4 micro-tile
// ---------------------------------------------------------------------------
__global__ __launch_bounds__(256) void sgemm_bias(
    const float* __restrict__ A, const float* __restrict__ B,
    const float* __restrict__ bias, float* __restrict__ C, int M) {
    __shared__ float As[BK][BM];   // transposed A tile
    __shared__ float Bs[BK][BN];
    int tid = threadIdx.x;
    int tx = tid & 15, ty = tid >> 4;
    int row0 = blockIdx.x * BM;
    int col0 = blockIdx.y * BN;
    float acc[4][4] = {};

    for (int k0 = 0; k0 < DIM; k0 += BK) {
#pragma unroll
        for (int l = 0; l < 2; ++l) {
            int f = tid + l * 256;             // 0..511 float4 slots
            // A tile: 64 rows x 32 k  (8 float4 per row)
            int ar = f >> 3;
            int ak = (f & 7) * 4;
            float4 av = make_float4(0.f, 0.f, 0.f, 0.f);
            if (row0 + ar < M)
                av = *reinterpret_cast<const float4*>(&A[(size_t)(row0 + ar) * DIM + k0 + ak]);
            As[ak + 0][ar] = av.x; As[ak + 1][ar] = av.y;
            As[ak + 2][ar] = av.z; As[ak + 3][ar] = av.w;
            // B tile: 32 rows x 64 n  (16 float4 per row)
            int br = f >> 4;
            int bn = (f & 15) * 4;
            *reinterpret_cast<float4*>(&Bs[br][bn]) =
                *reinterpret_cast<const float4*>(&B[(size_t)(k0 + br) * DIM + col0 + bn]);
        }
        __syncthreads();
#pragma unroll
        for (int kk = 0; kk < BK; ++kk) {
            float4 a4 = *reinterpret_cast<const float4*>(&As[kk][ty * 4]);
            float4 b4 = *reinterpret_cast<const float4*>(&Bs[kk][tx * 4]);
            float a[4] = {a4.x, a4.y, a4.z, a4.w};
            float b[4] = {b4.x, b4.y, b4.z, b4.w};
#pragma unroll
            for (int i = 0; i < 4; ++i)
#pragma unroll
                for (int j = 0; j < 4; ++j)
                    acc[i][j] += a[i] * b[j];
        }
        __syncthreads();
    }

    float4 bv = *reinterpret_cast<const float4*>(&bias[col0 + tx * 4]);
    float bb[4] = {bv.x, bv.y, bv.z, bv.w};
#pragma unroll
    for (int i = 0; i < 4; ++i) {
        int r = row0 + ty * 4 + i;
        if (r < M) {
            float4 o;
            o.x = acc[i][0] + bb[0];
            o.y = acc[i][1] + bb[1];
            o.z = acc[i][2] + bb[2];
            o.w = acc[i][3] + bb[3];
            *reinterpret_cast<float4*>(&C[(size_t)r * DIM + col0 + tx * 4]) = o;
        }
    }
}

// ---------------------------------------------------------------------------
// CSR build: histogram -> exclusive scan -> scatter col into buckets
// ---------------------------------------------------------------------------
__global__ void zero_ints(int* __restrict__ p, int n) {
    int i = blockIdx.x * blockDim.x + threadIdx.x;
    if (i < n) p[i] = 0;
}

__global__ void hist_rows(const int* __restrict__ row, int* __restrict__ cnt, int E) {
    int e = blockIdx.x * blockDim.x + threadIdx.x;
    if (e < E) atomicAdd(&cnt[row[e]], 1);
}

__global__ __launch_bounds__(1024) void exscan(const int* __restrict__ cnt,
                                               int* __restrict__ rowptr,
                                               int* __restrict__ cursor, int n) {
    __shared__ int sdata[1024];
    __shared__ int carry;
    if (threadIdx.x == 0) carry = 0;
    __syncthreads();
    for (int base = 0; base < n; base += 1024) {
        int idx = base + threadIdx.x;
        int v = (idx < n) ? cnt[idx] : 0;
        sdata[threadIdx.x] = v;
        __syncthreads();
        for (int off = 1; off < 1024; off <<= 1) {
            int t = sdata[threadIdx.x];
            int u = (threadIdx.x >= (unsigned)off) ? sdata[threadIdx.x - off] : 0;
            __syncthreads();
            sdata[threadIdx.x] = t + u;
            __syncthreads();
        }
        int incl = sdata[threadIdx.x];
        int excl = incl - v + carry;          // reads carry BEFORE update below
        if (idx < n) { rowptr[idx] = excl; cursor[idx] = excl; }
        __syncthreads();
        if (threadIdx.x == 1023) carry += sdata[1023];
        __syncthreads();
    }
    if (threadIdx.x == 0) rowptr[n] = carry;
}

__global__ void scatter_edges(const int* __restrict__ row, const int* __restrict__ col,
                              int* __restrict__ cursor, int* __restrict__ ecol, int E) {
    int e = blockIdx.x * blockDim.x + threadIdx.x;
    if (e < E) {
        int r = row[e];
        int p = atomicAdd(&cursor[r], 1);
        ecol[p] = col[e];
    }
}

// ---------------------------------------------------------------------------
// Fused sparse attention: one block (256 thr) per node.
// Thread t = h*32 + d holds q[i,h,d]; per edge, coalesced K/V row loads,
// 32-lane butterfly dot-product, direct exp (scores bounded ~|6| here),
// register accumulation. 2-deep prefetch of next edge's K/V rows.
// ---------------------------------------------------------------------------
__global__ __launch_bounds__(256) void attn_fused(
    const float* __restrict__ Q, const float* __restrict__ K, const float* __restrict__ V,
    const int* __restrict__ rowptr, const int* __restrict__ ecol,
    float* __restrict__ attn) {
    int i = blockIdx.x;
    int t = threadIdx.x;                 // t = h*32 + d
    float q = Q[(size_t)i * DIM + t];
    int start = rowptr[i], end = rowptr[i + 1];

    float z = 0.f, acc = 0.f;
    float k_next = 0.f, v_next = 0.f;
    if (start < end) {
        int c = ecol[start];
        k_next = K[(size_t)c * DIM + t];
        v_next = V[(size_t)c * DIM + t];
    }
    for (int j = start; j < end; ++j) {
        float kc = k_next, vc = v_next;
        if (j + 1 < end) {
            int c2 = ecol[j + 1];
            k_next = K[(size_t)c2 * DIM + t];
            v_next = V[(size_t)c2 * DIM + t];
        }
        float p = q * kc;
        p += __shfl_xor(p, 1, 32);
        p += __shfl_xor(p, 2, 32);
        p += __shfl_xor(p, 4, 32);
        p += __shfl_xor(p, 8, 32);
        p += __shfl_xor(p, 16, 32);      // all 32 lanes of the head group hold s
        float w = __expf(p);
        z += w;
        acc += w * vc;
    }
    float inv = (z > 0.f) ? 1.0f / z : 0.f;
    attn[(size_t)i * DIM + t] = acc * inv;
}

// ---------------------------------------------------------------------------
// Launch
// ---------------------------------------------------------------------------
extern "C" void kernel_launch(void* const* d_in, const int* in_sizes, int n_in,
                              void* d_out, int out_size, void* d_ws, size_t ws_size,
                              hipStream_t stream) {
    const float* x  = (const float*)d_in[0];
    const int*   row = (const int*)d_in[1];
    const int*   col = (const int*)d_in[2];
    const float* Wq = (const float*)d_in[3];
    const float* bq = (const float*)d_in[4];
    const float* Wk = (const float*)d_in[5];
    const float* bk = (const float*)d_in[6];
    const float* Wv = (const float*)d_in[7];
    const float* bv = (const float*)d_in[8];
    const float* Wo = (const float*)d_in[9];
    const float* bo = (const float*)d_in[10];
    int N = in_sizes[0] / DIM;
    int E = in_sizes[1];
    float* out = (float*)d_out;

    // workspace carve-up (~213 MB total)
    char* p = (char*)d_ws;
    auto alloc = [&](size_t bytes) {
        char* r = p;
        p += (bytes + 255) & ~(size_t)255;
        return r;
    };
    float* Q    = (float*)alloc((size_t)N * DIM * sizeof(float));
    float* Kb   = (float*)alloc((size_t)N * DIM * sizeof(float));
    float* Vb   = (float*)alloc((size_t)N * DIM * sizeof(float));
    float* attn = (float*)alloc((size_t)N * DIM * sizeof(float));
    float* Wqp  = (float*)alloc(DIM * DIM * sizeof(float));
    float* Wkp  = (float*)alloc(DIM * DIM * sizeof(float));
    float* Wvp  = (float*)alloc(DIM * DIM * sizeof(float));
    float* Wop  = (float*)alloc(DIM * DIM * sizeof(float));
    float* bqp  = (float*)alloc(DIM * sizeof(float));
    float* bkp  = (float*)alloc(DIM * sizeof(float));
    float* bvp  = (float*)alloc(DIM * sizeof(float));
    int* cnt    = (int*)alloc((size_t)N * sizeof(int));
    int* rowptr = (int*)alloc((size_t)(N + 1) * sizeof(int));
    int* cursor = (int*)alloc((size_t)N * sizeof(int));
    int* ecol   = (int*)alloc((size_t)E * sizeof(int));

    const float scaling = 0.17677669529663687f;   // 32^-0.5

    // 1) permute weights (fold q-scaling into Wq/bq)
    permute_w_cols<<<DIM * DIM / 256, 256, 0, stream>>>(Wq, Wqp, scaling);
    permute_w_cols<<<DIM * DIM / 256, 256, 0, stream>>>(Wk, Wkp, 1.0f);
    permute_w_cols<<<DIM * DIM / 256, 256, 0, stream>>>(Wv, Wvp, 1.0f);
    permute_w_rows<<<DIM * DIM / 256, 256, 0, stream>>>(Wo, Wop);
    permute_bias<<<1, 256, 0, stream>>>(bq, bqp, scaling);
    permute_bias<<<1, 256, 0, stream>>>(bk, bkp, 1.0f);
    permute_bias<<<1, 256, 0, stream>>>(bv, bvp, 1.0f);

    // 2) Q/K/V projections (head-contiguous layout)
    dim3 ggrid((N + BM - 1) / BM, DIM / BN);
    sgemm_bias<<<ggrid, 256, 0, stream>>>(x, Wqp, bqp, Q, N);
    sgemm_bias<<<ggrid, 256, 0, stream>>>(x, Wkp, bkp, Kb, N);
    sgemm_bias<<<ggrid, 256, 0, stream>>>(x, Wvp, bvp, Vb, N);

    // 3) CSR build
    zero_ints<<<(N + 255) / 256, 256, 0, stream>>>(cnt, N);
    hist_rows<<<(E + 255) / 256, 256, 0, stream>>>(row, cnt, E);
    exscan<<<1, 1024, 0, stream>>>(cnt, rowptr, cursor, N);
    scatter_edges<<<(E + 255) / 256, 256, 0, stream>>>(row, col, cursor, ecol, E);

    // 4) fused sparse attention
    attn_fused<<<N, 256, 0, stream>>>(Q, Kb, Vb, rowptr, ecol, attn);

    // 5) output projection
    sgemm_bias<<<ggrid, 256, 0, stream>>>(attn, Wop, bo, out, N);
}

// Round 2
// 633.468 us; speedup vs baseline: 1.8767x; 1.8767x over previous
//
#include <hip/hip_runtime.h>
#include <hip/hip_bf16.h>

#define DIM 256
#define NH 8
#define DH 32

typedef __attribute__((ext_vector_type(4))) float f32x4;
typedef __attribute__((ext_vector_type(8))) short bf16x8;

__device__ __forceinline__ float bf2f(unsigned short u) {
    union { unsigned int i; float f; } x; x.i = ((unsigned int)u) << 16; return x.f;
}
__device__ __forceinline__ unsigned short f2bf(float f) {
    union { float f; unsigned int i; } x; x.f = f;
    unsigned int r = x.i + 0x7fffu + ((x.i >> 16) & 1u);
    return (unsigned short)(r >> 16);
}

// ---------------------------------------------------------------------------
// Weight prep. Reference reshape (N, DH, NH): flat col c = d*NH + h.
// We use head-contiguous c' = h*DH + d, so orig col = (c'&31)*8 + (c'>>5).
// Store B transposed (BT[col][k]) in bf16 so MFMA B-fragments are 16B
// contiguous loads. Wq/bq get the 1/sqrt(32) scale folded in.
// ---------------------------------------------------------------------------
__global__ void build_wqkvT(const float* __restrict__ Wq, const float* __restrict__ Wk,
                            const float* __restrict__ Wv, unsigned short* __restrict__ WT) {
    int idx = blockIdx.x * 256 + threadIdx.x;          // [768][256]
    int r = idx >> 8, k = idx & 255;
    int cl = r & 255;
    int d = cl & 31, h = cl >> 5;
    int c = d * NH + h;
    const float* W = (r < 256) ? Wq : (r < 512 ? Wk : Wv);
    float scale = (r < 256) ? 0.17677669529663687f : 1.0f;
    WT[idx] = f2bf(W[k * DIM + c] * scale);
}

__global__ void build_bqkv(const float* __restrict__ bq, const float* __restrict__ bk,
                           const float* __restrict__ bv, float* __restrict__ bias) {
    int r = blockIdx.x * 256 + threadIdx.x;            // 768
    int cl = r & 255;
    int d = cl & 31, h = cl >> 5;
    int c = d * NH + h;
    const float* b = (r < 256) ? bq : (r < 512 ? bk : bv);
    float scale = (r < 256) ? 0.17677669529663687f : 1.0f;
    bias[r] = b[c] * scale;
}

__global__ void build_woT(const float* __restrict__ Wo, unsigned short* __restrict__ WT) {
    int idx = blockIdx.x * 256 + threadIdx.x;          // [256 j][256 c']
    int j = idx >> 8, cp = idx & 255;
    int d = cp & 31, h = cp >> 5;
    WT[idx] = f2bf(Wo[(d * NH + h) * DIM + j]);
}

__global__ void f32_to_bf16(const float* __restrict__ x, unsigned short* __restrict__ xb, int n) {
    int i = (blockIdx.x * 256 + threadIdx.x) * 4;
    if (i < n) {
        float4 v = *reinterpret_cast<const float4*>(x + i);
        ushort4 o;
        o.x = f2bf(v.x); o.y = f2bf(v.y); o.z = f2bf(v.z); o.w = f2bf(v.w);
        *reinterpret_cast<ushort4*>(xb + i) = o;
    }
}

// ---------------------------------------------------------------------------
// No-LDS MFMA GEMM: C[M][ldc] = A[M][256](bf16) @ BT[ldc][256]^T (bf16) + bias
// 128x128 tile, 4 waves (2x2), each wave 64x64 via 4x4 16x16x32 fragments.
// A-frag: lane row = l&15, k = (l>>4)*8..+7  (16B contiguous from row-major A)
// B-frag: lane col = l&15, same k            (16B contiguous from BT)
// D: col = l&15, row = (l>>4)*4 + reg.
// ---------------------------------------------------------------------------
template<int OUT_BF16>
__global__ __launch_bounds__(256) void gemm_mfma(
    const unsigned short* __restrict__ A, const unsigned short* __restrict__ BT,
    const float* __restrict__ bias, void* __restrict__ Cout, int M, int ldc) {
    int tid = threadIdx.x;
    int l = tid & 63, w = tid >> 6;
    int row0 = blockIdx.x * 128 + (w >> 1) * 64;
    int col0 = blockIdx.y * 128 + (w & 1) * 64;
    int lr = l & 15;
    int lk = (l >> 4) * 8;

    const unsigned short* Ap[4];
    const unsigned short* Bp[4];
#pragma unroll
    for (int m = 0; m < 4; ++m) {
        int r = row0 + m * 16 + lr;
        if (r >= M) r = M - 1;                 // clamp: junk rows never stored
        Ap[m] = A + (size_t)r * DIM + lk;
    }
#pragma unroll
    for (int n = 0; n < 4; ++n)
        Bp[n] = BT + (size_t)(col0 + n * 16 + lr) * DIM + lk;

    f32x4 acc[4][4] = {};
#pragma unroll
    for (int k0 = 0; k0 < DIM; k0 += 32) {
        bf16x8 a[4], b[4];
#pragma unroll
        for (int m = 0; m < 4; ++m) a[m] = *reinterpret_cast<const bf16x8*>(Ap[m] + k0);
#pragma unroll
        for (int n = 0; n < 4; ++n) b[n] = *reinterpret_cast<const bf16x8*>(Bp[n] + k0);
#pragma unroll
        for (int m = 0; m < 4; ++m)
#pragma unroll
            for (int n = 0; n < 4; ++n)
                acc[m][n] = __builtin_amdgcn_mfma_f32_16x16x32_bf16(a[m], b[n], acc[m][n], 0, 0, 0);
    }

    int rb = (l >> 4) * 4;
    int cc = l & 15;
#pragma unroll
    for (int n = 0; n < 4; ++n) {
        int c = col0 + n * 16 + cc;
        float bv = bias[c];
#pragma unroll
        for (int m = 0; m < 4; ++m) {
#pragma unroll
            for (int j = 0; j < 4; ++j) {
                int r = row0 + m * 16 + rb + j;
                if (r < M) {
                    float v = acc[m][n][j] + bv;
                    if (OUT_BF16) ((unsigned short*)Cout)[(size_t)r * ldc + c] = f2bf(v);
                    else          ((float*)Cout)[(size_t)r * ldc + c] = v;
                }
            }
        }
    }
}

// ---------------------------------------------------------------------------
// CSR build
// ---------------------------------------------------------------------------
__global__ void zero_ints(int* __restrict__ p, int n) {
    int i = blockIdx.x * blockDim.x + threadIdx.x;
    if (i < n) p[i] = 0;
}

__global__ void hist_rows(const int* __restrict__ row, int* __restrict__ cnt, int E) {
    int e = blockIdx.x * blockDim.x + threadIdx.x;
    if (e < E) atomicAdd(&cnt[row[e]], 1);
}

__global__ __launch_bounds__(1024) void exscan(const int* __restrict__ cnt,
                                               int* __restrict__ rowptr,
                                               int* __restrict__ cursor, int n) {
    __shared__ int wsum[16];
    __shared__ int carry_s;
    int tid = threadIdx.x;
    int l = tid & 63, w = tid >> 6;
    if (tid == 0) carry_s = 0;
    __syncthreads();
    for (int base = 0; base < n; base += 1024) {
        int idx = base + tid;
        int v = (idx < n) ? cnt[idx] : 0;
        int s = v;                                    // inclusive wave scan
#pragma unroll
        for (int off = 1; off < 64; off <<= 1) {
            int u = __shfl_up(s, off, 64);
            if (l >= off) s += u;
        }
        if (l == 63) wsum[w] = s;
        __syncthreads();
        if (w == 0) {
            int t = (l < 16) ? wsum[l] : 0;
#pragma unroll
            for (int off = 1; off < 16; off <<= 1) {
                int u = __shfl_up(t, off, 64);
                if (l >= off) t += u;
            }
            if (l < 16) wsum[l] = t;                  // inclusive scan of wave sums
        }
        __syncthreads();
        int excl = s - v + ((w > 0) ? wsum[w - 1] : 0) + carry_s;
        if (idx < n) { rowptr[idx] = excl; cursor[idx] = excl; }
        __syncthreads();
        if (tid == 1023) carry_s += wsum[15];
        __syncthreads();
    }
    if (tid == 0) rowptr[n] = carry_s;
}

__global__ void scatter_edges(const int* __restrict__ row, const int* __restrict__ col,
                              int* __restrict__ cursor, int* __restrict__ ecol, int E) {
    int e = blockIdx.x * blockDim.x + threadIdx.x;
    if (e < E) {
        int r = row[e];
        int p = atomicAdd(&cursor[r], 1);
        ecol[p] = col[e];
    }
}

// ---------------------------------------------------------------------------
// Fused sparse attention, one WAVE per node (4 nodes / 256-thr block).
// QKV[i] = [Q(256) | K(256) | V(256)] bf16, head-contiguous (c' = h*32+d).
// Lane l owns elements l*4..l*4+3 -> head h = l>>3; dot reduces over the
// 8-lane group. Per edge: two 8B ushort4 loads cover the 512B K and V rows.
// Depth-1 prefetch of the next edge's rows. Direct exp (scores bounded ~|6|).
// ---------------------------------------------------------------------------
__global__ __launch_bounds__(256) void attn_fused(
    const unsigned short* __restrict__ QKV,
    const int* __restrict__ rowptr, const int* __restrict__ ecol,
    unsigned short* __restrict__ attn, int N) {
    int i = blockIdx.x * 4 + (threadIdx.x >> 6);
    if (i >= N) return;
    int l = threadIdx.x & 63;

    ushort4 q4 = *reinterpret_cast<const ushort4*>(QKV + (size_t)i * 768 + l * 4);
    float q0 = bf2f(q4.x), q1 = bf2f(q4.y), q2 = bf2f(q4.z), q3 = bf2f(q4.w);

    int start = rowptr[i], end = rowptr[i + 1];
    float z = 0.f, a0 = 0.f, a1 = 0.f, a2 = 0.f, a3 = 0.f;

    ushort4 kp = make_ushort4(0, 0, 0, 0), vp = kp;
    if (start < end) {
        const unsigned short* b = QKV + (size_t)ecol[start] * 768;
        kp = *reinterpret_cast<const ushort4*>(b + 256 + l * 4);
        vp = *reinterpret_cast<const ushort4*>(b + 512 + l * 4);
    }
    for (int j = start; j < end; ++j) {
        ushort4 kc = kp, vc = vp;
        if (j + 1 < end) {
            const unsigned short* b = QKV + (size_t)ecol[j + 1] * 768;
            kp = *reinterpret_cast<const ushort4*>(b + 256 + l * 4);
            vp = *reinterpret_cast<const ushort4*>(b + 512 + l * 4);
        }
        float s = q0 * bf2f(kc.x) + q1 * bf2f(kc.y) + q2 * bf2f(kc.z) + q3 * bf2f(kc.w);
        s += __shfl_xor(s, 1, 64);
        s += __shfl_xor(s, 2, 64);
        s += __shfl_xor(s, 4, 64);                    // all 8 lanes of head hold s
        float wgt = __expf(s);
        z += wgt;
        a0 += wgt * bf2f(vc.x);
        a1 += wgt * bf2f(vc.y);
        a2 += wgt * bf2f(vc.z);
        a3 += wgt * bf2f(vc.w);
    }
    float inv = (z > 0.f) ? 1.0f / z : 0.f;
    ushort4 o;
    o.x = f2bf(a0 * inv); o.y = f2bf(a1 * inv);
    o.z = f2bf(a2 * inv); o.w = f2bf(a3 * inv);
    *reinterpret_cast<ushort4*>(attn + (size_t)i * 256 + l * 4) = o;
}

// ---------------------------------------------------------------------------
// Launch
// ---------------------------------------------------------------------------
extern "C" void kernel_launch(void* const* d_in, const int* in_sizes, int n_in,
                              void* d_out, int out_size, void* d_ws, size_t ws_size,
                              hipStream_t stream) {
    const float* x  = (const float*)d_in[0];
    const int*   row = (const int*)d_in[1];
    const int*   col = (const int*)d_in[2];
    const float* Wq = (const float*)d_in[3];
    const float* bq = (const float*)d_in[4];
    const float* Wk = (const float*)d_in[5];
    const float* bk = (const float*)d_in[6];
    const float* Wv = (const float*)d_in[7];
    const float* bv = (const float*)d_in[8];
    const float* Wo = (const float*)d_in[9];
    const float* bo = (const float*)d_in[10];
    int N = in_sizes[0] / DIM;
    int E = in_sizes[1];
    float* out = (float*)d_out;

    char* p = (char*)d_ws;
    auto alloc = [&](size_t bytes) {
        char* r = p;
        p += (bytes + 255) & ~(size_t)255;
        return r;
    };
    unsigned short* xb   = (unsigned short*)alloc((size_t)N * DIM * 2);        // 25.6 MB
    unsigned short* QKV  = (unsigned short*)alloc((size_t)N * 768 * 2);        // 76.8 MB
    unsigned short* attn = (unsigned short*)alloc((size_t)N * DIM * 2);        // 25.6 MB
    unsigned short* WqkvT = (unsigned short*)alloc((size_t)768 * DIM * 2);
    unsigned short* WoT   = (unsigned short*)alloc((size_t)DIM * DIM * 2);
    float* bqkv = (float*)alloc(768 * sizeof(float));
    int* cnt    = (int*)alloc((size_t)N * sizeof(int));
    int* rowptr = (int*)alloc((size_t)(N + 1) * sizeof(int));
    int* cursor = (int*)alloc((size_t)N * sizeof(int));
    int* ecol   = (int*)alloc((size_t)E * sizeof(int));

    // weight prep + input conversion
    build_wqkvT<<<768, 256, 0, stream>>>(Wq, Wk, Wv, WqkvT);
    build_woT<<<256, 256, 0, stream>>>(Wo, WoT);
    build_bqkv<<<3, 256, 0, stream>>>(bq, bk, bv, bqkv);
    f32_to_bf16<<<(N * DIM / 4 + 255) / 256, 256, 0, stream>>>(x, xb, N * DIM);

    // CSR build (overlappable with QKV GEMM in the queue)
    zero_ints<<<(N + 255) / 256, 256, 0, stream>>>(cnt, N);
    hist_rows<<<(E + 255) / 256, 256, 0, stream>>>(row, cnt, E);
    exscan<<<1, 1024, 0, stream>>>(cnt, rowptr, cursor, N);
    scatter_edges<<<(E + 255) / 256, 256, 0, stream>>>(row, col, cursor, ecol, E);

    // fused QKV projection -> bf16 interleaved [N][768]
    dim3 g1((N + 127) / 128, 768 / 128);
    gemm_mfma<1><<<g1, 256, 0, stream>>>(xb, WqkvT, bqkv, QKV, N, 768);

    // fused sparse attention -> bf16 [N][256]
    attn_fused<<<(N + 3) / 4, 256, 0, stream>>>(QKV, rowptr, ecol, attn, N);

    // output projection -> f32 out
    dim3 g2((N + 127) / 128, 2);
    gemm_mfma<0><<<g2, 256, 0, stream>>>(attn, WoT, bo, out, N, DIM);
}

// Round 3
// 577.455 us; speedup vs baseline: 2.0587x; 1.0970x over previous
//
#include <hip/hip_runtime.h>
#include <hip/hip_bf16.h>

#define DIM 256
#define NH 8
#define DH 32

typedef __attribute__((ext_vector_type(4))) float f32x4;
typedef __attribute__((ext_vector_type(8))) short bf16x8;
typedef __attribute__((ext_vector_type(8))) unsigned short u16x8;

__device__ __forceinline__ float bf2f(unsigned short u) {
    union { unsigned int i; float f; } x; x.i = ((unsigned int)u) << 16; return x.f;
}
__device__ __forceinline__ unsigned short f2bf(float f) {
    union { float f; unsigned int i; } x; x.f = f;
    unsigned int r = x.i + 0x7fffu + ((x.i >> 16) & 1u);
    return (unsigned short)(r >> 16);
}

// ---------------------------------------------------------------------------
// Layouts.
// QKV record per node (768 bf16): [0..255]=Q head-contig (c'=h*32+d),
// [256..767]=KV lane-interleaved: lane l owns {k[4l..4l+3], v[4l..4l+3]} 16B.
// Tiled GEMM operand layout (for A and BT): per 128-row tile R, per K-step ks
// (BK=64), per 16B k-block kb (8), per row (128): 8 elems.
//   off(R,ks,kb,row,j) = R*32768 + ks*8192 + kb*1024 + row*8 + j
// This equals the LDS layout, so staging is a contiguous 16KB copy and
// ds_read_b128 fragment reads are lane-contiguous (conflict-free).
// ---------------------------------------------------------------------------

// output col o (0..767) of QKV projection -> (src matrix, orig weight col)
__device__ __forceinline__ void map_col(int o, int& which, int& c) {
    int cp;
    if (o < 256) { which = 0; cp = o; }
    else {
        int u = o - 256;
        int lane = u >> 3, slot = u & 7;
        which = (slot < 4) ? 1 : 2;
        cp = lane * 4 + (slot & 3);
    }
    c = (cp & 31) * 8 + (cp >> 5);   // reference reshape: c = d*NH + h
}

__global__ void build_wqkvT(const float* __restrict__ Wq, const float* __restrict__ Wk,
                            const float* __restrict__ Wv, unsigned short* __restrict__ Bt) {
    int idx = blockIdx.x * 256 + threadIdx.x;      // 768*256 elems, tiled layout
    int CB = idx >> 15;
    int rem = idx & 32767;
    int ks = rem >> 13, kb = (rem >> 10) & 7, ci = (rem >> 3) & 127, jj = rem & 7;
    int o = CB * 128 + ci;
    int k = ks * 64 + kb * 8 + jj;
    int which, c; map_col(o, which, c);
    const float* W = (which == 0) ? Wq : (which == 1 ? Wk : Wv);
    float scale = (which == 0) ? 0.17677669529663687f : 1.0f;
    Bt[idx] = f2bf(W[k * DIM + c] * scale);
}

__global__ void build_bqkv(const float* __restrict__ bq, const float* __restrict__ bk,
                           const float* __restrict__ bv, float* __restrict__ bias) {
    int o = blockIdx.x * 256 + threadIdx.x;        // 768
    int which, c; map_col(o, which, c);
    const float* b = (which == 0) ? bq : (which == 1 ? bk : bv);
    float scale = (which == 0) ? 0.17677669529663687f : 1.0f;
    bias[o] = b[c] * scale;
}

__global__ void build_woT(const float* __restrict__ Wo, unsigned short* __restrict__ Bt) {
    int idx = blockIdx.x * 256 + threadIdx.x;      // 256*256 elems, tiled layout
    int CB = idx >> 15;
    int rem = idx & 32767;
    int ks = rem >> 13, kb = (rem >> 10) & 7, ci = (rem >> 3) & 127, jj = rem & 7;
    int o = CB * 128 + ci;                         // output col j of Wo
    int cp = ks * 64 + kb * 8 + jj;                // k index = attn col c'
    Bt[idx] = f2bf(Wo[((cp & 31) * 8 + (cp >> 5)) * DIM + o]);
}

// x [M][256] f32 -> tiled bf16
__global__ void conv_x_tiled(const float* __restrict__ x, unsigned short* __restrict__ xt, int M) {
    int idx = blockIdx.x * 256 + threadIdx.x;      // one thread per 8 elems
    int r = idx >> 5;
    if (r >= M) return;
    int kc = (idx & 31) * 8;
    float4 v0 = *reinterpret_cast<const float4*>(x + (size_t)r * DIM + kc);
    float4 v1 = *reinterpret_cast<const float4*>(x + (size_t)r * DIM + kc + 4);
    u16x8 o;
    o[0] = f2bf(v0.x); o[1] = f2bf(v0.y); o[2] = f2bf(v0.z); o[3] = f2bf(v0.w);
    o[4] = f2bf(v1.x); o[5] = f2bf(v1.y); o[6] = f2bf(v1.z); o[7] = f2bf(v1.w);
    int R = r >> 7, row = r & 127, ks = kc >> 6, kb = (kc & 63) >> 3;
    *reinterpret_cast<u16x8*>(xt + (size_t)R * 32768 + ks * 8192 + kb * 1024 + row * 8) = o;
}

// ---------------------------------------------------------------------------
// LDS-staged MFMA GEMM. A tiled [Rtiles][4][8][128][8], BT tiled likewise.
// 128x128 tile, 4 waves (2x2), BK=64, single-buffered, global_load_lds 16B.
// C row-major [M][ldc] (+bias), bf16 or f32.
// ---------------------------------------------------------------------------
#define GLOAD_LDS16(gp, lp) \
    __builtin_amdgcn_global_load_lds( \
        (const __attribute__((address_space(1))) unsigned int*)(gp), \
        (__attribute__((address_space(3))) unsigned int*)(lp), 16, 0, 0)

template<int OUT_BF16>
__global__ __launch_bounds__(256) void gemm_tiled(
    const unsigned short* __restrict__ At, const unsigned short* __restrict__ Bt,
    const float* __restrict__ bias, void* __restrict__ Cout, int M, int ldc) {
    __shared__ unsigned short lds[16384];          // A 16KB @0, B 16KB @8192
    int tid = threadIdx.x;
    int l = tid & 63, w = tid >> 6;
    const unsigned short* Abase = At + (size_t)blockIdx.x * 32768;
    const unsigned short* Bbase = Bt + (size_t)blockIdx.y * 32768;

    int rbase = (w >> 1) * 64 + (l & 15);
    int cbase = (w & 1) * 64 + (l & 15);
    int kq = l >> 4;

    f32x4 acc[4][4] = {};
#pragma unroll
    for (int ks = 0; ks < 4; ++ks) {
        if (ks) __syncthreads();                   // all reads of prev tile done
#pragma unroll
        for (int i = 0; i < 4; ++i) {
            GLOAD_LDS16(Abase + (size_t)ks * 8192 + i * 2048 + tid * 8, &lds[i * 2048 + tid * 8]);
            GLOAD_LDS16(Bbase + (size_t)ks * 8192 + i * 2048 + tid * 8, &lds[8192 + i * 2048 + tid * 8]);
        }
        __syncthreads();                           // drains vmcnt -> LDS ready
#pragma unroll
        for (int kk = 0; kk < 2; ++kk) {
            int kb = kk * 4 + kq;
            bf16x8 a[4], b[4];
#pragma unroll
            for (int m = 0; m < 4; ++m)
                a[m] = *reinterpret_cast<const bf16x8*>(&lds[kb * 1024 + (rbase + m * 16) * 8]);
#pragma unroll
            for (int n = 0; n < 4; ++n)
                b[n] = *reinterpret_cast<const bf16x8*>(&lds[8192 + kb * 1024 + (cbase + n * 16) * 8]);
#pragma unroll
            for (int m = 0; m < 4; ++m)
#pragma unroll
                for (int n = 0; n < 4; ++n)
                    acc[m][n] = __builtin_amdgcn_mfma_f32_16x16x32_bf16(a[m], b[n], acc[m][n], 0, 0, 0);
        }
    }

    int row0 = blockIdx.x * 128 + (w >> 1) * 64;
    int col0 = blockIdx.y * 128 + (w & 1) * 64;
    int rb = (l >> 4) * 4, cc = l & 15;
#pragma unroll
    for (int n = 0; n < 4; ++n) {
        int c = col0 + n * 16 + cc;
        float bv = bias[c];
#pragma unroll
        for (int m = 0; m < 4; ++m) {
#pragma unroll
            for (int j = 0; j < 4; ++j) {
                int r = row0 + m * 16 + rb + j;
                if (r < M) {
                    float v = acc[m][n][j] + bv;
                    if (OUT_BF16) ((unsigned short*)Cout)[(size_t)r * ldc + c] = f2bf(v);
                    else          ((float*)Cout)[(size_t)r * ldc + c] = v;
                }
            }
        }
    }
}

// ---------------------------------------------------------------------------
// CSR build
// ---------------------------------------------------------------------------
__global__ void zero_ints(int* __restrict__ p, int n) {
    int i = blockIdx.x * blockDim.x + threadIdx.x;
    if (i < n) p[i] = 0;
}

__global__ void hist_rows(const int* __restrict__ row, int* __restrict__ cnt, int E) {
    int e = blockIdx.x * blockDim.x + threadIdx.x;
    if (e < E) atomicAdd(&cnt[row[e]], 1);
}

__global__ __launch_bounds__(1024) void exscan(const int* __restrict__ cnt,
                                               int* __restrict__ rowptr,
                                               int* __restrict__ cursor, int n) {
    __shared__ int wsum[16];
    __shared__ int carry_s;
    int tid = threadIdx.x;
    int l = tid & 63, w = tid >> 6;
    if (tid == 0) carry_s = 0;
    __syncthreads();
    for (int base = 0; base < n; base += 1024) {
        int idx = base + tid;
        int v = (idx < n) ? cnt[idx] : 0;
        int s = v;
#pragma unroll
        for (int off = 1; off < 64; off <<= 1) {
            int u = __shfl_up(s, off, 64);
            if (l >= off) s += u;
        }
        if (l == 63) wsum[w] = s;
        __syncthreads();
        if (w == 0) {
            int t = (l < 16) ? wsum[l] : 0;
#pragma unroll
            for (int off = 1; off < 16; off <<= 1) {
                int u = __shfl_up(t, off, 64);
                if (l >= off) t += u;
            }
            if (l < 16) wsum[l] = t;
        }
        __syncthreads();
        int excl = s - v + ((w > 0) ? wsum[w - 1] : 0) + carry_s;
        if (idx < n) { rowptr[idx] = excl; cursor[idx] = excl; }
        __syncthreads();
        if (tid == 1023) carry_s += wsum[15];
        __syncthreads();
    }
    if (tid == 0) rowptr[n] = carry_s;
}

__global__ void scatter_edges(const int* __restrict__ row, const int* __restrict__ col,
                              int* __restrict__ cursor, int* __restrict__ ecol, int E) {
    int e = blockIdx.x * blockDim.x + threadIdx.x;
    if (e < E) {
        int r = row[e];
        int p = atomicAdd(&cursor[r], 1);
        ecol[p] = col[e];
    }
}

// ---------------------------------------------------------------------------
// Fused sparse attention, one wave per node, KV-interleaved records,
// depth-3 rotating prefetch. Output written in the tiled GEMM-A layout.
// ---------------------------------------------------------------------------
__global__ __launch_bounds__(256) void attn_fused(
    const unsigned short* __restrict__ QKV,
    const int* __restrict__ rowptr, const int* __restrict__ ecol,
    unsigned short* __restrict__ attn_t, int N) {
    int i = blockIdx.x * 4 + (threadIdx.x >> 6);
    if (i >= N) return;
    int l = threadIdx.x & 63;

    ushort4 q4 = *reinterpret_cast<const ushort4*>(QKV + (size_t)i * 768 + l * 4);
    float q0 = bf2f(q4.x), q1 = bf2f(q4.y), q2 = bf2f(q4.z), q3 = bf2f(q4.w);

    int j = rowptr[i], end = rowptr[i + 1];
    float z = 0.f, a0 = 0.f, a1 = 0.f, a2 = 0.f, a3 = 0.f;

#define LKV(jj) (*reinterpret_cast<const u16x8*>(QKV + (size_t)ecol[jj] * 768 + 256 + l * 8))
    u16x8 kvA = {}, kvB = {}, kvC = {};
    if (j < end)     kvA = LKV(j);
    if (j + 1 < end) kvB = LKV(j + 1);
    if (j + 2 < end) kvC = LKV(j + 2);

#define STEP(KV) { \
        float s = q0 * bf2f(KV[0]) + q1 * bf2f(KV[1]) + q2 * bf2f(KV[2]) + q3 * bf2f(KV[3]); \
        s += __shfl_xor(s, 1, 64); \
        s += __shfl_xor(s, 2, 64); \
        s += __shfl_xor(s, 4, 64); \
        float wgt = __expf(s); \
        z += wgt; \
        a0 += wgt * bf2f(KV[4]); a1 += wgt * bf2f(KV[5]); \
        a2 += wgt * bf2f(KV[6]); a3 += wgt * bf2f(KV[7]); \
        if (j + 3 < end) KV = LKV(j + 3); \
        ++j; }

    while (j < end) {
        STEP(kvA);
        if (j < end) STEP(kvB);
        if (j < end) STEP(kvC);
    }
#undef STEP
#undef LKV

    float inv = (z > 0.f) ? 1.0f / z : 0.f;
    ushort4 o;
    o.x = f2bf(a0 * inv); o.y = f2bf(a1 * inv);
    o.z = f2bf(a2 * inv); o.w = f2bf(a3 * inv);
    // tiled store: c' = 4l
    int R = i >> 7, row = i & 127;
    int ks = l >> 4, kb = (l & 15) >> 1, j4 = (l & 1) * 4;
    *reinterpret_cast<ushort4*>(attn_t + (size_t)R * 32768 + ks * 8192 + kb * 1024 + row * 8 + j4) = o;
}

// ---------------------------------------------------------------------------
// Launch
// ---------------------------------------------------------------------------
extern "C" void kernel_launch(void* const* d_in, const int* in_sizes, int n_in,
                              void* d_out, int out_size, void* d_ws, size_t ws_size,
                              hipStream_t stream) {
    const float* x  = (const float*)d_in[0];
    const int*   row = (const int*)d_in[1];
    const int*   col = (const int*)d_in[2];
    const float* Wq = (const float*)d_in[3];
    const float* bq = (const float*)d_in[4];
    const float* Wk = (const float*)d_in[5];
    const float* bk = (const float*)d_in[6];
    const float* Wv = (const float*)d_in[7];
    const float* bv = (const float*)d_in[8];
    const float* Wo = (const float*)d_in[9];
    const float* bo = (const float*)d_in[10];
    int N = in_sizes[0] / DIM;
    int E = in_sizes[1];
    float* out = (float*)d_out;

    int Rtiles = (N + 127) / 128;

    char* p = (char*)d_ws;
    auto alloc = [&](size_t bytes) {
        char* r = p;
        p += (bytes + 255) & ~(size_t)255;
        return r;
    };
    unsigned short* xt     = (unsigned short*)alloc((size_t)Rtiles * 32768 * 2);
    unsigned short* QKV    = (unsigned short*)alloc((size_t)N * 768 * 2);
    unsigned short* attn_t = (unsigned short*)alloc((size_t)Rtiles * 32768 * 2);
    unsigned short* WqkvT  = (unsigned short*)alloc((size_t)768 * DIM * 2);
    unsigned short* WoT    = (unsigned short*)alloc((size_t)DIM * DIM * 2);
    float* bqkv = (float*)alloc(768 * sizeof(float));
    int* cnt    = (int*)alloc((size_t)N * sizeof(int));
    int* rowptr = (int*)alloc((size_t)(N + 1) * sizeof(int));
    int* cursor = (int*)alloc((size_t)N * sizeof(int));
    int* ecol   = (int*)alloc((size_t)E * sizeof(int));

    // weight prep + input conversion (tiled layouts)
    build_wqkvT<<<768, 256, 0, stream>>>(Wq, Wk, Wv, WqkvT);
    build_woT<<<256, 256, 0, stream>>>(Wo, WoT);
    build_bqkv<<<3, 256, 0, stream>>>(bq, bk, bv, bqkv);
    conv_x_tiled<<<(N * 32 + 255) / 256, 256, 0, stream>>>(x, xt, N);

    // CSR build
    zero_ints<<<(N + 255) / 256, 256, 0, stream>>>(cnt, N);
    hist_rows<<<(E + 255) / 256, 256, 0, stream>>>(row, cnt, E);
    exscan<<<1, 1024, 0, stream>>>(cnt, rowptr, cursor, N);
    scatter_edges<<<(E + 255) / 256, 256, 0, stream>>>(row, col, cursor, ecol, E);

    // fused QKV projection -> bf16 records [N][768]
    dim3 g1(Rtiles, 6);
    gemm_tiled<1><<<g1, 256, 0, stream>>>(xt, WqkvT, bqkv, QKV, N, 768);

    // fused sparse attention -> tiled bf16
    attn_fused<<<(N + 3) / 4, 256, 0, stream>>>(QKV, rowptr, ecol, attn_t, N);

    // output projection -> f32 out
    dim3 g2(Rtiles, 2);
    gemm_tiled<0><<<g2, 256, 0, stream>>>(attn_t, WoT, bo, out, N, DIM);
}

// Round 4
// 546.537 us; speedup vs baseline: 2.1752x; 1.0566x over previous
//
#include <hip/hip_runtime.h>
#include <hip/hip_bf16.h>

#define DIM 256
#define NH 8

typedef __attribute__((ext_vector_type(4))) float f32x4;
typedef __attribute__((ext_vector_type(8))) short bf16x8;
typedef __attribute__((ext_vector_type(8))) unsigned short u16x8;

__device__ __forceinline__ float bf2f(unsigned short u) {
    union { unsigned int i; float f; } x; x.i = ((unsigned int)u) << 16; return x.f;
}
__device__ __forceinline__ unsigned short f2bf(float f) {
    union { float f; unsigned int i; } x; x.f = f;
    unsigned int r = x.i + 0x7fffu + ((x.i >> 16) & 1u);
    return (unsigned short)(r >> 16);
}

// ---------------------------------------------------------------------------
// Layouts (unchanged from round 3).
// QKV record per node (768 bf16): [0..255]=Q head-contig, [256..767]=KV
// lane-interleaved (lane l owns {k[4l..4l+3], v[4l..4l+3]} = 16B).
// Tiled GEMM operand layout: off(R,ks,kb,row,j)=R*32768+ks*8192+kb*1024+row*8+j
// == the LDS layout, so staging is a contiguous copy; ds_read_b128 is
// lane-contiguous (conflict-free).
// ---------------------------------------------------------------------------
__device__ __forceinline__ void map_col(int o, int& which, int& c) {
    int cp;
    if (o < 256) { which = 0; cp = o; }
    else {
        int u = o - 256;
        int lane = u >> 3, slot = u & 7;
        which = (slot < 4) ? 1 : 2;
        cp = lane * 4 + (slot & 3);
    }
    c = (cp & 31) * 8 + (cp >> 5);   // reference reshape: c = d*NH + h
}

// One kernel builds WqkvT (tiled), WoT (tiled), bqkv.
__global__ void build_weights(const float* __restrict__ Wq, const float* __restrict__ Wk,
                              const float* __restrict__ Wv, const float* __restrict__ Wo,
                              const float* __restrict__ bq, const float* __restrict__ bk,
                              const float* __restrict__ bv,
                              unsigned short* __restrict__ WqkvT,
                              unsigned short* __restrict__ WoT,
                              float* __restrict__ bqkv) {
    int idx = blockIdx.x * 256 + threadIdx.x;
    if (idx < 768 * 256) {
        int CB = idx >> 15;
        int rem = idx & 32767;
        int ks = rem >> 13, kb = (rem >> 10) & 7, ci = (rem >> 3) & 127, jj = rem & 7;
        int o = CB * 128 + ci;
        int k = ks * 64 + kb * 8 + jj;
        int which, c; map_col(o, which, c);
        const float* W = (which == 0) ? Wq : (which == 1 ? Wk : Wv);
        float scale = (which == 0) ? 0.17677669529663687f : 1.0f;
        WqkvT[idx] = f2bf(W[k * DIM + c] * scale);
    } else if (idx < 768 * 256 + 256 * 256) {
        int id2 = idx - 768 * 256;
        int CB = id2 >> 15;
        int rem = id2 & 32767;
        int ks = rem >> 13, kb = (rem >> 10) & 7, ci = (rem >> 3) & 127, jj = rem & 7;
        int o = CB * 128 + ci;
        int cp = ks * 64 + kb * 8 + jj;
        WoT[id2] = f2bf(Wo[((cp & 31) * 8 + (cp >> 5)) * DIM + o]);
    } else if (idx < 768 * 256 + 256 * 256 + 768) {
        int o = idx - (768 * 256 + 256 * 256);
        int which, c; map_col(o, which, c);
        const float* b = (which == 0) ? bq : (which == 1 ? bk : bv);
        float scale = (which == 0) ? 0.17677669529663687f : 1.0f;
        bqkv[o] = b[c] * scale;
    }
}

// x [M][256] f32 -> tiled bf16
__global__ void conv_x_tiled(const float* __restrict__ x, unsigned short* __restrict__ xt, int M) {
    int idx = blockIdx.x * 256 + threadIdx.x;
    int r = idx >> 5;
    if (r >= M) return;
    int kc = (idx & 31) * 8;
    float4 v0 = *reinterpret_cast<const float4*>(x + (size_t)r * DIM + kc);
    float4 v1 = *reinterpret_cast<const float4*>(x + (size_t)r * DIM + kc + 4);
    u16x8 o;
    o[0] = f2bf(v0.x); o[1] = f2bf(v0.y); o[2] = f2bf(v0.z); o[3] = f2bf(v0.w);
    o[4] = f2bf(v1.x); o[5] = f2bf(v1.y); o[6] = f2bf(v1.z); o[7] = f2bf(v1.w);
    int R = r >> 7, row = r & 127, ks = kc >> 6, kb = (kc & 63) >> 3;
    *reinterpret_cast<u16x8*>(xt + (size_t)R * 32768 + ks * 8192 + kb * 1024 + row * 8) = o;
}

// ---------------------------------------------------------------------------
// LDS-staged MFMA GEMM, 2-deep double-buffered pipeline with counted vmcnt.
// 128x128 tile, 4 waves (2x2), BK=64, 64KB LDS (2 bufs x (A 16KB + B 16KB)).
// ---------------------------------------------------------------------------
#define GLOAD_LDS16(gp, lp) \
    __builtin_amdgcn_global_load_lds( \
        (const __attribute__((address_space(1))) unsigned int*)(gp), \
        (__attribute__((address_space(3))) unsigned int*)(lp), 16, 0, 0)

template<int OUT_BF16>
__global__ __launch_bounds__(256) void gemm_tiled(
    const unsigned short* __restrict__ At, const unsigned short* __restrict__ Bt,
    const float* __restrict__ bias, void* __restrict__ Cout, int M, int ldc) {
    __shared__ unsigned short lds[32768];          // 64KB: buf0 @0, buf1 @16384
    int tid = threadIdx.x;
    int l = tid & 63, w = tid >> 6;
    const unsigned short* Abase = At + (size_t)blockIdx.x * 32768;
    const unsigned short* Bbase = Bt + (size_t)blockIdx.y * 32768;

    int rbase = (w >> 1) * 64 + (l & 15);
    int cbase = (w & 1) * 64 + (l & 15);
    int kq = l >> 4;

    auto stage = [&](int ks, int buf) {
        unsigned short* lb = &lds[buf * 16384];
#pragma unroll
        for (int i = 0; i < 4; ++i) {
            GLOAD_LDS16(Abase + ks * 8192 + i * 2048 + tid * 8, &lb[i * 2048 + tid * 8]);
            GLOAD_LDS16(Bbase + ks * 8192 + i * 2048 + tid * 8, &lb[8192 + i * 2048 + tid * 8]);
        }
    };

    f32x4 acc[4][4] = {};
    stage(0, 0);
    stage(1, 1);
#pragma unroll
    for (int ks = 0; ks < 4; ++ks) {
        if (ks < 3) asm volatile("s_waitcnt vmcnt(8)" ::: "memory");
        else        asm volatile("s_waitcnt vmcnt(0)" ::: "memory");
        __builtin_amdgcn_s_barrier();
        __builtin_amdgcn_sched_barrier(0);
        const unsigned short* lb = &lds[(ks & 1) * 16384];
#pragma unroll
        for (int kk = 0; kk < 2; ++kk) {
            int kb = kk * 4 + kq;
            bf16x8 a[4], b[4];
#pragma unroll
            for (int m = 0; m < 4; ++m)
                a[m] = *reinterpret_cast<const bf16x8*>(&lb[kb * 1024 + (rbase + m * 16) * 8]);
#pragma unroll
            for (int n = 0; n < 4; ++n)
                b[n] = *reinterpret_cast<const bf16x8*>(&lb[8192 + kb * 1024 + (cbase + n * 16) * 8]);
#pragma unroll
            for (int m = 0; m < 4; ++m)
#pragma unroll
                for (int n = 0; n < 4; ++n)
                    acc[m][n] = __builtin_amdgcn_mfma_f32_16x16x32_bf16(a[m], b[n], acc[m][n], 0, 0, 0);
        }
        if (ks < 2) {                              // refill the buffer just freed
            __builtin_amdgcn_sched_barrier(0);
            __builtin_amdgcn_s_barrier();          // all waves done reading buf
            stage(ks + 2, ks & 1);
        }
    }

    int row0 = blockIdx.x * 128 + (w >> 1) * 64;
    int col0 = blockIdx.y * 128 + (w & 1) * 64;
    int rb = (l >> 4) * 4, cc = l & 15;
#pragma unroll
    for (int n = 0; n < 4; ++n) {
        int c = col0 + n * 16 + cc;
        float bv = bias[c];
#pragma unroll
        for (int m = 0; m < 4; ++m) {
#pragma unroll
            for (int j = 0; j < 4; ++j) {
                int r = row0 + m * 16 + rb + j;
                if (r < M) {
                    float v = acc[m][n][j] + bv;
                    if (OUT_BF16) ((unsigned short*)Cout)[(size_t)r * ldc + c] = f2bf(v);
                    else          ((float*)Cout)[(size_t)r * ldc + c] = v;
                }
            }
        }
    }
}

// ---------------------------------------------------------------------------
// CSR build: histogram -> multi-block scan (3 small kernels) -> scatter
// ---------------------------------------------------------------------------
__global__ void hist_rows(const int* __restrict__ row, int* __restrict__ cnt, int E) {
    int e = blockIdx.x * blockDim.x + threadIdx.x;
    if (e < E) atomicAdd(&cnt[row[e]], 1);
}

__global__ __launch_bounds__(256) void scan_partial(const int* __restrict__ cnt,
                                                    int* __restrict__ part, int n) {
    __shared__ int ws[4];
    int base = blockIdx.x * 1024 + threadIdx.x * 4;
    int s = 0;
    if (base + 3 < n) {
        int4 v = *reinterpret_cast<const int4*>(cnt + base);
        s = v.x + v.y + v.z + v.w;
    } else {
#pragma unroll
        for (int k = 0; k < 4; ++k) if (base + k < n) s += cnt[base + k];
    }
#pragma unroll
    for (int off = 1; off < 64; off <<= 1) s += __shfl_xor(s, off, 64);
    if ((threadIdx.x & 63) == 0) ws[threadIdx.x >> 6] = s;
    __syncthreads();
    if (threadIdx.x == 0) part[blockIdx.x] = ws[0] + ws[1] + ws[2] + ws[3];
}

__global__ void scan_chunks(int* __restrict__ part, int nch, int* __restrict__ rowptr, int n) {
    int l = threadIdx.x;                           // one wave
    int carry = 0;
    for (int base = 0; base < nch; base += 64) {
        int idx = base + l;
        int v = (idx < nch) ? part[idx] : 0;
        int s = v;
#pragma unroll
        for (int off = 1; off < 64; off <<= 1) {
            int u = __shfl_up(s, off, 64);
            if (l >= off) s += u;
        }
        if (idx < nch) part[idx] = s - v + carry;  // exclusive
        carry += __shfl(s, 63, 64);
    }
    if (l == 0) rowptr[n] = carry;
}

__global__ __launch_bounds__(256) void scan_final(const int* __restrict__ cnt,
                                                  const int* __restrict__ part,
                                                  int* __restrict__ rowptr,
                                                  int* __restrict__ cursor, int n) {
    __shared__ int ws[4];
    int tid = threadIdx.x, l = tid & 63, w = tid >> 6;
    int base = blockIdx.x * 1024 + tid * 4;
    int v[4] = {0, 0, 0, 0};
    if (base + 3 < n) {
        int4 t = *reinterpret_cast<const int4*>(cnt + base);
        v[0] = t.x; v[1] = t.y; v[2] = t.z; v[3] = t.w;
    } else {
#pragma unroll
        for (int k = 0; k < 4; ++k) if (base + k < n) v[k] = cnt[base + k];
    }
    int tsum = v[0] + v[1] + v[2] + v[3];
    int s = tsum;
#pragma unroll
    for (int off = 1; off < 64; off <<= 1) {
        int u = __shfl_up(s, off, 64);
        if (l >= off) s += u;
    }
    if (l == 63) ws[w] = s;
    __syncthreads();
    int woff = 0;
    for (int k = 0; k < w; ++k) woff += ws[k];
    int run = part[blockIdx.x] + woff + s - tsum;
#pragma unroll
    for (int k = 0; k < 4; ++k) {
        int idx = base + k;
        if (idx < n) { rowptr[idx] = run; cursor[idx] = run; }
        run += v[k];
    }
}

__global__ void scatter_edges(const int* __restrict__ row, const int* __restrict__ col,
                              int* __restrict__ cursor, int* __restrict__ ecol, int E) {
    int e = blockIdx.x * blockDim.x + threadIdx.x;
    if (e < E) {
        int r = row[e];
        int p = atomicAdd(&cursor[r], 1);
        ecol[p] = col[e];
    }
}

// ---------------------------------------------------------------------------
// Fused sparse attention, one wave per node. Depth-4 KV pipeline with a
// decoupled column ring (cols fetched 4 steps ahead of their KV issue,
// clamped to the last edge -> straight-line, branch-free refills).
// ---------------------------------------------------------------------------
__global__ __launch_bounds__(256) void attn_fused(
    const unsigned short* __restrict__ QKV,
    const int* __restrict__ rowptr, const int* __restrict__ ecol,
    unsigned short* __restrict__ attn_t, int N) {
    int i = blockIdx.x * 4 + (threadIdx.x >> 6);
    if (i >= N) return;
    int l = threadIdx.x & 63;

    ushort4 q4 = *reinterpret_cast<const ushort4*>(QKV + (size_t)i * 768 + l * 4);
    float q0 = bf2f(q4.x), q1 = bf2f(q4.y), q2 = bf2f(q4.z), q3 = bf2f(q4.w);

    int j = rowptr[i], end = rowptr[i + 1];
    float z = 0.f, a0 = 0.f, a1 = 0.f, a2 = 0.f, a3 = 0.f;

    if (j < end) {
        int last = end - 1;
#define CL(jj) ecol[(jj) < last ? (jj) : last]
#define KVL(c) (*reinterpret_cast<const u16x8*>(QKV + (size_t)(c) * 768 + 256 + l * 8))
        int cA = CL(j), cB = CL(j + 1), cC = CL(j + 2), cD = CL(j + 3);
        u16x8 kvA = KVL(cA), kvB = KVL(cB), kvC = KVL(cC), kvD = KVL(cD);
        int r0 = CL(j + 4), r1 = CL(j + 5), r2 = CL(j + 6), r3 = CL(j + 7);

#define STEP(KV) { \
        float s = q0 * bf2f(KV[0]) + q1 * bf2f(KV[1]) + q2 * bf2f(KV[2]) + q3 * bf2f(KV[3]); \
        s += __shfl_xor(s, 1, 64); \
        s += __shfl_xor(s, 2, 64); \
        s += __shfl_xor(s, 4, 64); \
        float wgt = __expf(s); \
        z += wgt; \
        a0 += wgt * bf2f(KV[4]); a1 += wgt * bf2f(KV[5]); \
        a2 += wgt * bf2f(KV[6]); a3 += wgt * bf2f(KV[7]); \
        KV = KVL(r0); r0 = r1; r1 = r2; r2 = r3; r3 = CL(j + 8); \
        ++j; }

        while (j < end) {
            STEP(kvA);
            if (j < end) STEP(kvB);
            if (j < end) STEP(kvC);
            if (j < end) STEP(kvD);
        }
#undef STEP
#undef KVL
#undef CL
    }

    float inv = (z > 0.f) ? 1.0f / z : 0.f;
    ushort4 o;
    o.x = f2bf(a0 * inv); o.y = f2bf(a1 * inv);
    o.z = f2bf(a2 * inv); o.w = f2bf(a3 * inv);
    int R = i >> 7, row = i & 127;
    int ks = l >> 4, kb = (l & 15) >> 1, j4 = (l & 1) * 4;
    *reinterpret_cast<ushort4*>(attn_t + (size_t)R * 32768 + ks * 8192 + kb * 1024 + row * 8 + j4) = o;
}

// ---------------------------------------------------------------------------
// Launch
// ---------------------------------------------------------------------------
extern "C" void kernel_launch(void* const* d_in, const int* in_sizes, int n_in,
                              void* d_out, int out_size, void* d_ws, size_t ws_size,
                              hipStream_t stream) {
    const float* x  = (const float*)d_in[0];
    const int*   row = (const int*)d_in[1];
    const int*   col = (const int*)d_in[2];
    const float* Wq = (const float*)d_in[3];
    const float* bq = (const float*)d_in[4];
    const float* Wk = (const float*)d_in[5];
    const float* bk = (const float*)d_in[6];
    const float* Wv = (const float*)d_in[7];
    const float* bv = (const float*)d_in[8];
    const float* Wo = (const float*)d_in[9];
    const float* bo = (const float*)d_in[10];
    int N = in_sizes[0] / DIM;
    int E = in_sizes[1];
    float* out = (float*)d_out;

    int Rtiles = (N + 127) / 128;
    int nch = (N + 1023) / 1024;

    char* p = (char*)d_ws;
    auto alloc = [&](size_t bytes) {
        char* r = p;
        p += (bytes + 255) & ~(size_t)255;
        return r;
    };
    unsigned short* xt     = (unsigned short*)alloc((size_t)Rtiles * 32768 * 2);
    unsigned short* QKV    = (unsigned short*)alloc((size_t)N * 768 * 2);
    unsigned short* attn_t = (unsigned short*)alloc((size_t)Rtiles * 32768 * 2);
    unsigned short* WqkvT  = (unsigned short*)alloc((size_t)768 * DIM * 2);
    unsigned short* WoT    = (unsigned short*)alloc((size_t)DIM * DIM * 2);
    float* bqkv = (float*)alloc(768 * sizeof(float));
    int* cnt    = (int*)alloc((size_t)N * sizeof(int));
    int* part   = (int*)alloc((size_t)nch * sizeof(int));
    int* rowptr = (int*)alloc((size_t)(N + 1) * sizeof(int));
    int* cursor = (int*)alloc((size_t)N * sizeof(int));
    int* ecol   = (int*)alloc((size_t)E * sizeof(int));

    // weight prep + input conversion
    build_weights<<<(768 * 256 + 256 * 256 + 768 + 255) / 256, 256, 0, stream>>>(
        Wq, Wk, Wv, Wo, bq, bk, bv, WqkvT, WoT, bqkv);
    conv_x_tiled<<<(N * 32 + 255) / 256, 256, 0, stream>>>(x, xt, N);

    // CSR build
    hipMemsetAsync(cnt, 0, (size_t)N * sizeof(int), stream);
    hist_rows<<<(E + 255) / 256, 256, 0, stream>>>(row, cnt, E);
    scan_partial<<<nch, 256, 0, stream>>>(cnt, part, N);
    scan_chunks<<<1, 64, 0, stream>>>(part, nch, rowptr, N);
    scan_final<<<nch, 256, 0, stream>>>(cnt, part, rowptr, cursor, N);
    scatter_edges<<<(E + 255) / 256, 256, 0, stream>>>(row, col, cursor, ecol, E);

    // fused QKV projection -> bf16 records [N][768]
    dim3 g1(Rtiles, 6);
    gemm_tiled<1><<<g1, 256, 0, stream>>>(xt, WqkvT, bqkv, QKV, N, 768);

    // fused sparse attention -> tiled bf16
    attn_fused<<<(N + 3) / 4, 256, 0, stream>>>(QKV, rowptr, ecol, attn_t, N);

    // output projection -> f32 out
    dim3 g2(Rtiles, 2);
    gemm_tiled<0><<<g2, 256, 0, stream>>>(attn_t, WoT, bo, out, N, DIM);
}

// Round 5
// 541.536 us; speedup vs baseline: 2.1953x; 1.0092x over previous
//
#include <hip/hip_runtime.h>
#include <hip/hip_bf16.h>

#define DIM 256
#define NH 8

typedef __attribute__((ext_vector_type(4))) float f32x4;
typedef __attribute__((ext_vector_type(8))) short bf16x8;
typedef __attribute__((ext_vector_type(8))) unsigned short u16x8;

__device__ __forceinline__ float bf2f(unsigned short u) {
    union { unsigned int i; float f; } x; x.i = ((unsigned int)u) << 16; return x.f;
}
__device__ __forceinline__ unsigned short f2bf(float f) {
    union { float f; unsigned int i; } x; x.f = f;
    unsigned int r = x.i + 0x7fffu + ((x.i >> 16) & 1u);
    return (unsigned short)(r >> 16);
}

// ---------------------------------------------------------------------------
// Layouts.
// QKV record per node (768 bf16): [0..255]=Q head-contig, [256..767]=KV
// lane-interleaved (lane l owns {k[4l..4l+3], v[4l..4l+3]} = 16B).
// Tiled GEMM operand layout: off(R,ks,kb,row,j)=R*32768+ks*8192+kb*1024+row*8+j
// == the LDS layout, so staging is a contiguous copy; ds_read_b128 is
// lane-contiguous (conflict-free).
// ---------------------------------------------------------------------------
__device__ __forceinline__ void map_col(int o, int& which, int& c) {
    int cp;
    if (o < 256) { which = 0; cp = o; }
    else {
        int u = o - 256;
        int lane = u >> 3, slot = u & 7;
        which = (slot < 4) ? 1 : 2;
        cp = lane * 4 + (slot & 3);
    }
    c = (cp & 31) * 8 + (cp >> 5);   // reference reshape: c = d*NH + h
}

// Fused prep: WqkvT (tiled), WoT (tiled), bqkv, and x -> tiled bf16.
// idx regions: [0, 196608) WqkvT | [196608, 262144) WoT | [262144, 262912)
// bqkv | [W0, W0 + M*32) conv_x (one thread per 8 elems).
#define PREP_W0 262912
__global__ void prep_fused(const float* __restrict__ Wq, const float* __restrict__ Wk,
                           const float* __restrict__ Wv, const float* __restrict__ Wo,
                           const float* __restrict__ bq, const float* __restrict__ bk,
                           const float* __restrict__ bv, const float* __restrict__ x,
                           unsigned short* __restrict__ WqkvT,
                           unsigned short* __restrict__ WoT,
                           float* __restrict__ bqkv,
                           unsigned short* __restrict__ xt, int M) {
    int idx = blockIdx.x * 256 + threadIdx.x;
    if (idx < 768 * 256) {
        int CB = idx >> 15;
        int rem = idx & 32767;
        int ks = rem >> 13, kb = (rem >> 10) & 7, ci = (rem >> 3) & 127, jj = rem & 7;
        int o = CB * 128 + ci;
        int k = ks * 64 + kb * 8 + jj;
        int which, c; map_col(o, which, c);
        const float* W = (which == 0) ? Wq : (which == 1 ? Wk : Wv);
        float scale = (which == 0) ? 0.17677669529663687f : 1.0f;
        WqkvT[idx] = f2bf(W[k * DIM + c] * scale);
    } else if (idx < 768 * 256 + 256 * 256) {
        int id2 = idx - 768 * 256;
        int CB = id2 >> 15;
        int rem = id2 & 32767;
        int ks = rem >> 13, kb = (rem >> 10) & 7, ci = (rem >> 3) & 127, jj = rem & 7;
        int o = CB * 128 + ci;
        int cp = ks * 64 + kb * 8 + jj;
        WoT[id2] = f2bf(Wo[((cp & 31) * 8 + (cp >> 5)) * DIM + o]);
    } else if (idx < PREP_W0) {
        int o = idx - (768 * 256 + 256 * 256);
        if (o < 768) {
            int which, c; map_col(o, which, c);
            const float* b = (which == 0) ? bq : (which == 1 ? bk : bv);
            float scale = (which == 0) ? 0.17677669529663687f : 1.0f;
            bqkv[o] = b[c] * scale;
        }
    } else {
        int t = idx - PREP_W0;
        int r = t >> 5;
        if (r >= M) return;
        int kc = (t & 31) * 8;
        float4 v0 = *reinterpret_cast<const float4*>(x + (size_t)r * DIM + kc);
        float4 v1 = *reinterpret_cast<const float4*>(x + (size_t)r * DIM + kc + 4);
        u16x8 o;
        o[0] = f2bf(v0.x); o[1] = f2bf(v0.y); o[2] = f2bf(v0.z); o[3] = f2bf(v0.w);
        o[4] = f2bf(v1.x); o[5] = f2bf(v1.y); o[6] = f2bf(v1.z); o[7] = f2bf(v1.w);
        int R = r >> 7, row = r & 127, ks = kc >> 6, kb = (kc & 63) >> 3;
        *reinterpret_cast<u16x8*>(xt + (size_t)R * 32768 + ks * 8192 + kb * 1024 + row * 8) = o;
    }
}

// ---------------------------------------------------------------------------
// LDS-staged MFMA GEMM (m97-style: single buffer, __syncthreads, compiler-
// managed waits). 128x128 tile, 4 waves (2x2), BK=64, 32KB LDS -> 4-5
// blocks/CU for inter-block overlap.
// ---------------------------------------------------------------------------
#define GLOAD_LDS16(gp, lp) \
    __builtin_amdgcn_global_load_lds( \
        (const __attribute__((address_space(1))) unsigned int*)(gp), \
        (__attribute__((address_space(3))) unsigned int*)(lp), 16, 0, 0)

template<int OUT_BF16>
__global__ __launch_bounds__(256) void gemm_tiled(
    const unsigned short* __restrict__ At, const unsigned short* __restrict__ Bt,
    const float* __restrict__ bias, void* __restrict__ Cout, int M, int ldc) {
    __shared__ unsigned short lds[16384];          // A 16KB @0, B 16KB @8192
    int tid = threadIdx.x;
    int l = tid & 63, w = tid >> 6;
    const unsigned short* Abase = At + (size_t)blockIdx.x * 32768;
    const unsigned short* Bbase = Bt + (size_t)blockIdx.y * 32768;

    int rbase = (w >> 1) * 64 + (l & 15);
    int cbase = (w & 1) * 64 + (l & 15);
    int kq = l >> 4;

    f32x4 acc[4][4] = {};
#pragma unroll
    for (int ks = 0; ks < 4; ++ks) {
        if (ks) __syncthreads();
#pragma unroll
        for (int i = 0; i < 4; ++i) {
            GLOAD_LDS16(Abase + (size_t)ks * 8192 + i * 2048 + tid * 8, &lds[i * 2048 + tid * 8]);
            GLOAD_LDS16(Bbase + (size_t)ks * 8192 + i * 2048 + tid * 8, &lds[8192 + i * 2048 + tid * 8]);
        }
        __syncthreads();
#pragma unroll
        for (int kk = 0; kk < 2; ++kk) {
            int kb = kk * 4 + kq;
            bf16x8 a[4], b[4];
#pragma unroll
            for (int m = 0; m < 4; ++m)
                a[m] = *reinterpret_cast<const bf16x8*>(&lds[kb * 1024 + (rbase + m * 16) * 8]);
#pragma unroll
            for (int n = 0; n < 4; ++n)
                b[n] = *reinterpret_cast<const bf16x8*>(&lds[8192 + kb * 1024 + (cbase + n * 16) * 8]);
#pragma unroll
            for (int m = 0; m < 4; ++m)
#pragma unroll
                for (int n = 0; n < 4; ++n)
                    acc[m][n] = __builtin_amdgcn_mfma_f32_16x16x32_bf16(a[m], b[n], acc[m][n], 0, 0, 0);
        }
    }

    int row0 = blockIdx.x * 128 + (w >> 1) * 64;
    int col0 = blockIdx.y * 128 + (w & 1) * 64;
    int rb = (l >> 4) * 4, cc = l & 15;
#pragma unroll
    for (int n = 0; n < 4; ++n) {
        int c = col0 + n * 16 + cc;
        float bv = bias[c];
#pragma unroll
        for (int m = 0; m < 4; ++m) {
#pragma unroll
            for (int j = 0; j < 4; ++j) {
                int r = row0 + m * 16 + rb + j;
                if (r < M) {
                    float v = acc[m][n][j] + bv;
                    if (OUT_BF16) ((unsigned short*)Cout)[(size_t)r * ldc + c] = f2bf(v);
                    else          ((float*)Cout)[(size_t)r * ldc + c] = v;
                }
            }
        }
    }
}

// ---------------------------------------------------------------------------
// CSR build: histogram -> multi-block scan -> scatter
// ---------------------------------------------------------------------------
__global__ void hist_rows(const int* __restrict__ row, int* __restrict__ cnt, int E) {
    int e = blockIdx.x * blockDim.x + threadIdx.x;
    if (e < E) atomicAdd(&cnt[row[e]], 1);
}

__global__ __launch_bounds__(256) void scan_partial(const int* __restrict__ cnt,
                                                    int* __restrict__ part, int n) {
    __shared__ int ws[4];
    int base = blockIdx.x * 1024 + threadIdx.x * 4;
    int s = 0;
    if (base + 3 < n) {
        int4 v = *reinterpret_cast<const int4*>(cnt + base);
        s = v.x + v.y + v.z + v.w;
    } else {
#pragma unroll
        for (int k = 0; k < 4; ++k) if (base + k < n) s += cnt[base + k];
    }
#pragma unroll
    for (int off = 1; off < 64; off <<= 1) s += __shfl_xor(s, off, 64);
    if ((threadIdx.x & 63) == 0) ws[threadIdx.x >> 6] = s;
    __syncthreads();
    if (threadIdx.x == 0) part[blockIdx.x] = ws[0] + ws[1] + ws[2] + ws[3];
}

__global__ void scan_chunks(int* __restrict__ part, int nch, int* __restrict__ rowptr, int n) {
    int l = threadIdx.x;                           // one wave
    int carry = 0;
    for (int base = 0; base < nch; base += 64) {
        int idx = base + l;
        int v = (idx < nch) ? part[idx] : 0;
        int s = v;
#pragma unroll
        for (int off = 1; off < 64; off <<= 1) {
            int u = __shfl_up(s, off, 64);
            if (l >= off) s += u;
        }
        if (idx < nch) part[idx] = s - v + carry;  // exclusive
        carry += __shfl(s, 63, 64);
    }
    if (l == 0) rowptr[n] = carry;
}

__global__ __launch_bounds__(256) void scan_final(const int* __restrict__ cnt,
                                                  const int* __restrict__ part,
                                                  int* __restrict__ rowptr,
                                                  int* __restrict__ cursor, int n) {
    __shared__ int ws[4];
    int tid = threadIdx.x, l = tid & 63, w = tid >> 6;
    int base = blockIdx.x * 1024 + tid * 4;
    int v[4] = {0, 0, 0, 0};
    if (base + 3 < n) {
        int4 t = *reinterpret_cast<const int4*>(cnt + base);
        v[0] = t.x; v[1] = t.y; v[2] = t.z; v[3] = t.w;
    } else {
#pragma unroll
        for (int k = 0; k < 4; ++k) if (base + k < n) v[k] = cnt[base + k];
    }
    int tsum = v[0] + v[1] + v[2] + v[3];
    int s = tsum;
#pragma unroll
    for (int off = 1; off < 64; off <<= 1) {
        int u = __shfl_up(s, off, 64);
        if (l >= off) s += u;
    }
    if (l == 63) ws[w] = s;
    __syncthreads();
    int woff = 0;
    for (int k = 0; k < w; ++k) woff += ws[k];
    int run = part[blockIdx.x] + woff + s - tsum;
#pragma unroll
    for (int k = 0; k < 4; ++k) {
        int idx = base + k;
        if (idx < n) { rowptr[idx] = run; cursor[idx] = run; }
        run += v[k];
    }
}

__global__ void scatter_edges(const int* __restrict__ row, const int* __restrict__ col,
                              int* __restrict__ cursor, int* __restrict__ ecol, int E) {
    int e = blockIdx.x * blockDim.x + threadIdx.x;
    if (e < E) {
        int r = row[e];
        int p = atomicAdd(&cursor[r], 1);
        ecol[p] = col[e];
    }
}

// ---------------------------------------------------------------------------
// Fused sparse attention, one wave per node, depth-4 KV pipeline with a
// clamped column ring. Launched in 4 destination-range slices (profiling
// visibility; per-node work is independent).
// ---------------------------------------------------------------------------
__global__ __launch_bounds__(256) void attn_fused(
    const unsigned short* __restrict__ QKV,
    const int* __restrict__ rowptr, const int* __restrict__ ecol,
    unsigned short* __restrict__ attn_t, int i0, int i1) {
    int i = i0 + blockIdx.x * 4 + (threadIdx.x >> 6);
    if (i >= i1) return;
    int l = threadIdx.x & 63;

    ushort4 q4 = *reinterpret_cast<const ushort4*>(QKV + (size_t)i * 768 + l * 4);
    float q0 = bf2f(q4.x), q1 = bf2f(q4.y), q2 = bf2f(q4.z), q3 = bf2f(q4.w);

    int j = rowptr[i], end = rowptr[i + 1];
    float z = 0.f, a0 = 0.f, a1 = 0.f, a2 = 0.f, a3 = 0.f;

    if (j < end) {
        int last = end - 1;
#define CL(jj) ecol[(jj) < last ? (jj) : last]
#define KVL(c) (*reinterpret_cast<const u16x8*>(QKV + (size_t)(c) * 768 + 256 + l * 8))
        int cA = CL(j), cB = CL(j + 1), cC = CL(j + 2), cD = CL(j + 3);
        u16x8 kvA = KVL(cA), kvB = KVL(cB), kvC = KVL(cC), kvD = KVL(cD);
        int r0 = CL(j + 4), r1 = CL(j + 5), r2 = CL(j + 6), r3 = CL(j + 7);

#define STEP(KV) { \
        float s = q0 * bf2f(KV[0]) + q1 * bf2f(KV[1]) + q2 * bf2f(KV[2]) + q3 * bf2f(KV[3]); \
        s += __shfl_xor(s, 1, 64); \
        s += __shfl_xor(s, 2, 64); \
        s += __shfl_xor(s, 4, 64); \
        float wgt = __expf(s); \
        z += wgt; \
        a0 += wgt * bf2f(KV[4]); a1 += wgt * bf2f(KV[5]); \
        a2 += wgt * bf2f(KV[6]); a3 += wgt * bf2f(KV[7]); \
        KV = KVL(r0); r0 = r1; r1 = r2; r2 = r3; r3 = CL(j + 8); \
        ++j; }

        while (j < end) {
            STEP(kvA);
            if (j < end) STEP(kvB);
            if (j < end) STEP(kvC);
            if (j < end) STEP(kvD);
        }
#undef STEP
#undef KVL
#undef CL
    }

    float inv = (z > 0.f) ? 1.0f / z : 0.f;
    ushort4 o;
    o.x = f2bf(a0 * inv); o.y = f2bf(a1 * inv);
    o.z = f2bf(a2 * inv); o.w = f2bf(a3 * inv);
    int R = i >> 7, row = i & 127;
    int ks = l >> 4, kb = (l & 15) >> 1, j4 = (l & 1) * 4;
    *reinterpret_cast<ushort4*>(attn_t + (size_t)R * 32768 + ks * 8192 + kb * 1024 + row * 8 + j4) = o;
}

// ---------------------------------------------------------------------------
// Launch
// ---------------------------------------------------------------------------
extern "C" void kernel_launch(void* const* d_in, const int* in_sizes, int n_in,
                              void* d_out, int out_size, void* d_ws, size_t ws_size,
                              hipStream_t stream) {
    const float* x  = (const float*)d_in[0];
    const int*   row = (const int*)d_in[1];
    const int*   col = (const int*)d_in[2];
    const float* Wq = (const float*)d_in[3];
    const float* bq = (const float*)d_in[4];
    const float* Wk = (const float*)d_in[5];
    const float* bk = (const float*)d_in[6];
    const float* Wv = (const float*)d_in[7];
    const float* bv = (const float*)d_in[8];
    const float* Wo = (const float*)d_in[9];
    const float* bo = (const float*)d_in[10];
    int N = in_sizes[0] / DIM;
    int E = in_sizes[1];
    float* out = (float*)d_out;

    int Rtiles = (N + 127) / 128;
    int nch = (N + 1023) / 1024;

    char* p = (char*)d_ws;
    auto alloc = [&](size_t bytes) {
        char* r = p;
        p += (bytes + 255) & ~(size_t)255;
        return r;
    };
    unsigned short* xt     = (unsigned short*)alloc((size_t)Rtiles * 32768 * 2);
    unsigned short* QKV    = (unsigned short*)alloc((size_t)N * 768 * 2);
    unsigned short* attn_t = (unsigned short*)alloc((size_t)Rtiles * 32768 * 2);
    unsigned short* WqkvT  = (unsigned short*)alloc((size_t)768 * DIM * 2);
    unsigned short* WoT    = (unsigned short*)alloc((size_t)DIM * DIM * 2);
    float* bqkv = (float*)alloc(768 * sizeof(float));
    int* cnt    = (int*)alloc((size_t)N * sizeof(int));
    int* part   = (int*)alloc((size_t)nch * sizeof(int));
    int* rowptr = (int*)alloc((size_t)(N + 1) * sizeof(int));
    int* cursor = (int*)alloc((size_t)N * sizeof(int));
    int* ecol   = (int*)alloc((size_t)E * sizeof(int));

    // fused prep: weights + biases + x conversion
    int prep_items = PREP_W0 + N * 32;
    prep_fused<<<(prep_items + 255) / 256, 256, 0, stream>>>(
        Wq, Wk, Wv, Wo, bq, bk, bv, x, WqkvT, WoT, bqkv, xt, N);

    // CSR build
    hipMemsetAsync(cnt, 0, (size_t)N * sizeof(int), stream);
    hist_rows<<<(E + 255) / 256, 256, 0, stream>>>(row, cnt, E);
    scan_partial<<<nch, 256, 0, stream>>>(cnt, part, N);
    scan_chunks<<<1, 64, 0, stream>>>(part, nch, rowptr, N);
    scan_final<<<nch, 256, 0, stream>>>(cnt, part, rowptr, cursor, N);
    scatter_edges<<<(E + 255) / 256, 256, 0, stream>>>(row, col, cursor, ecol, E);

    // fused QKV projection -> bf16 records [N][768]
    dim3 g1(Rtiles, 6);
    gemm_tiled<1><<<g1, 256, 0, stream>>>(xt, WqkvT, bqkv, QKV, N, 768);

    // fused sparse attention in 4 slices (per-dispatch profiling visibility)
    int q4n = (N + 3) / 4;
    for (int s4 = 0; s4 < 4; ++s4) {
        int i0 = s4 * q4n;
        int i1 = (s4 == 3) ? N : (s4 + 1) * q4n;
        if (i0 >= i1) continue;
        attn_fused<<<(i1 - i0 + 3) / 4, 256, 0, stream>>>(QKV, rowptr, ecol, attn_t, i0, i1);
    }

    // output projection -> f32 out
    dim3 g2(Rtiles, 2);
    gemm_tiled<0><<<g2, 256, 0, stream>>>(attn_t, WoT, bo, out, N, DIM);
}

// Round 6
// 487.728 us; speedup vs baseline: 2.4375x; 1.1103x over previous
//
#include <hip/hip_runtime.h>
#include <hip/hip_bf16.h>

#define DIM 256
#define NH 8

typedef __attribute__((ext_vector_type(4))) float f32x4;
typedef __attribute__((ext_vector_type(8))) short bf16x8;
typedef __attribute__((ext_vector_type(8))) unsigned short u16x8;

__device__ __forceinline__ float bf2f(unsigned short u) {
    union { unsigned int i; float f; } x; x.i = ((unsigned int)u) << 16; return x.f;
}
__device__ __forceinline__ unsigned short f2bf(float f) {
    union { float f; unsigned int i; } x; x.f = f;
    unsigned int r = x.i + 0x7fffu + ((x.i >> 16) & 1u);
    return (unsigned short)(r >> 16);
}

// ---------------------------------------------------------------------------
// Layouts.
// QKV record per node (768 bf16): [0..255]=Q head-contig, [256..767]=KV
// lane-interleaved (lane l owns {k[4l..4l+3], v[4l..4l+3]} = 16B).
// Tiled GEMM operand layout: off(R,ks,kb,row,j)=R*32768+ks*8192+kb*1024+row*8+j
// == the LDS layout, so staging is a contiguous copy; ds_read_b128 is
// lane-contiguous (conflict-free).
// Edge sort: coarse buckets of 512 rows (NB = ceil(N/512)); packed edge
// record = (row<<16)|col (requires N <= 65536, true here: N=50000).
// ---------------------------------------------------------------------------
__device__ __forceinline__ void map_col(int o, int& which, int& c) {
    int cp;
    if (o < 256) { which = 0; cp = o; }
    else {
        int u = o - 256;
        int lane = u >> 3, slot = u & 7;
        which = (slot < 4) ? 1 : 2;
        cp = lane * 4 + (slot & 3);
    }
    c = (cp & 31) * 8 + (cp >> 5);   // reference reshape: c = d*NH + h
}

// Fused prep: WqkvT (tiled), WoT (tiled), bqkv, and x -> tiled bf16.
#define PREP_W0 262912
__global__ void prep_fused(const float* __restrict__ Wq, const float* __restrict__ Wk,
                           const float* __restrict__ Wv, const float* __restrict__ Wo,
                           const float* __restrict__ bq, const float* __restrict__ bk,
                           const float* __restrict__ bv, const float* __restrict__ x,
                           unsigned short* __restrict__ WqkvT,
                           unsigned short* __restrict__ WoT,
                           float* __restrict__ bqkv,
                           unsigned short* __restrict__ xt, int M) {
    int idx = blockIdx.x * 256 + threadIdx.x;
    if (idx < 768 * 256) {
        int CB = idx >> 15;
        int rem = idx & 32767;
        int ks = rem >> 13, kb = (rem >> 10) & 7, ci = (rem >> 3) & 127, jj = rem & 7;
        int o = CB * 128 + ci;
        int k = ks * 64 + kb * 8 + jj;
        int which, c; map_col(o, which, c);
        const float* W = (which == 0) ? Wq : (which == 1 ? Wk : Wv);
        float scale = (which == 0) ? 0.17677669529663687f : 1.0f;
        WqkvT[idx] = f2bf(W[k * DIM + c] * scale);
    } else if (idx < 768 * 256 + 256 * 256) {
        int id2 = idx - 768 * 256;
        int CB = id2 >> 15;
        int rem = id2 & 32767;
        int ks = rem >> 13, kb = (rem >> 10) & 7, ci = (rem >> 3) & 127, jj = rem & 7;
        int o = CB * 128 + ci;
        int cp = ks * 64 + kb * 8 + jj;
        WoT[id2] = f2bf(Wo[((cp & 31) * 8 + (cp >> 5)) * DIM + o]);
    } else if (idx < PREP_W0) {
        int o = idx - (768 * 256 + 256 * 256);
        if (o < 768) {
            int which, c; map_col(o, which, c);
            const float* b = (which == 0) ? bq : (which == 1 ? bk : bv);
            float scale = (which == 0) ? 0.17677669529663687f : 1.0f;
            bqkv[o] = b[c] * scale;
        }
    } else {
        int t = idx - PREP_W0;
        int r = t >> 5;
        if (r >= M) return;
        int kc = (t & 31) * 8;
        float4 v0 = *reinterpret_cast<const float4*>(x + (size_t)r * DIM + kc);
        float4 v1 = *reinterpret_cast<const float4*>(x + (size_t)r * DIM + kc + 4);
        u16x8 o;
        o[0] = f2bf(v0.x); o[1] = f2bf(v0.y); o[2] = f2bf(v0.z); o[3] = f2bf(v0.w);
        o[4] = f2bf(v1.x); o[5] = f2bf(v1.y); o[6] = f2bf(v1.z); o[7] = f2bf(v1.w);
        int R = r >> 7, row = r & 127, ks = kc >> 6, kb = (kc & 63) >> 3;
        *reinterpret_cast<u16x8*>(xt + (size_t)R * 32768 + ks * 8192 + kb * 1024 + row * 8) = o;
    }
}

// ---------------------------------------------------------------------------
// LDS-staged MFMA GEMM (m97-style). 128x128 tile, 4 waves, BK=64, 32KB LDS.
// ---------------------------------------------------------------------------
#define GLOAD_LDS16(gp, lp) \
    __builtin_amdgcn_global_load_lds( \
        (const __attribute__((address_space(1))) unsigned int*)(gp), \
        (__attribute__((address_space(3))) unsigned int*)(lp), 16, 0, 0)

template<int OUT_BF16>
__global__ __launch_bounds__(256) void gemm_tiled(
    const unsigned short* __restrict__ At, const unsigned short* __restrict__ Bt,
    const float* __restrict__ bias, void* __restrict__ Cout, int M, int ldc) {
    __shared__ unsigned short lds[16384];          // A 16KB @0, B 16KB @8192
    int tid = threadIdx.x;
    int l = tid & 63, w = tid >> 6;
    const unsigned short* Abase = At + (size_t)blockIdx.x * 32768;
    const unsigned short* Bbase = Bt + (size_t)blockIdx.y * 32768;

    int rbase = (w >> 1) * 64 + (l & 15);
    int cbase = (w & 1) * 64 + (l & 15);
    int kq = l >> 4;

    f32x4 acc[4][4] = {};
#pragma unroll
    for (int ks = 0; ks < 4; ++ks) {
        if (ks) __syncthreads();
#pragma unroll
        for (int i = 0; i < 4; ++i) {
            GLOAD_LDS16(Abase + (size_t)ks * 8192 + i * 2048 + tid * 8, &lds[i * 2048 + tid * 8]);
            GLOAD_LDS16(Bbase + (size_t)ks * 8192 + i * 2048 + tid * 8, &lds[8192 + i * 2048 + tid * 8]);
        }
        __syncthreads();
#pragma unroll
        for (int kk = 0; kk < 2; ++kk) {
            int kb = kk * 4 + kq;
            bf16x8 a[4], b[4];
#pragma unroll
            for (int m = 0; m < 4; ++m)
                a[m] = *reinterpret_cast<const bf16x8*>(&lds[kb * 1024 + (rbase + m * 16) * 8]);
#pragma unroll
            for (int n = 0; n < 4; ++n)
                b[n] = *reinterpret_cast<const bf16x8*>(&lds[8192 + kb * 1024 + (cbase + n * 16) * 8]);
#pragma unroll
            for (int m = 0; m < 4; ++m)
#pragma unroll
                for (int n = 0; n < 4; ++n)
                    acc[m][n] = __builtin_amdgcn_mfma_f32_16x16x32_bf16(a[m], b[n], acc[m][n], 0, 0, 0);
        }
    }

    int row0 = blockIdx.x * 128 + (w >> 1) * 64;
    int col0 = blockIdx.y * 128 + (w & 1) * 64;
    int rb = (l >> 4) * 4, cc = l & 15;
#pragma unroll
    for (int n = 0; n < 4; ++n) {
        int c = col0 + n * 16 + cc;
        float bv = bias[c];
#pragma unroll
        for (int m = 0; m < 4; ++m) {
#pragma unroll
            for (int j = 0; j < 4; ++j) {
                int r = row0 + m * 16 + rb + j;
                if (r < M) {
                    float v = acc[m][n][j] + bv;
                    if (OUT_BF16) ((unsigned short*)Cout)[(size_t)r * ldc + c] = f2bf(v);
                    else          ((float*)Cout)[(size_t)r * ldc + c] = v;
                }
            }
        }
    }
}

// ---------------------------------------------------------------------------
// CSR build: histogram -> multi-block scan (rowptr)
// ---------------------------------------------------------------------------
__global__ void hist_rows(const int* __restrict__ row, int* __restrict__ cnt, int E) {
    int e = blockIdx.x * blockDim.x + threadIdx.x;
    if (e < E) atomicAdd(&cnt[row[e]], 1);
}

__global__ __launch_bounds__(256) void scan_partial(const int* __restrict__ cnt,
                                                    int* __restrict__ part, int n) {
    __shared__ int ws[4];
    int base = blockIdx.x * 1024 + threadIdx.x * 4;
    int s = 0;
    if (base + 3 < n) {
        int4 v = *reinterpret_cast<const int4*>(cnt + base);
        s = v.x + v.y + v.z + v.w;
    } else {
#pragma unroll
        for (int k = 0; k < 4; ++k) if (base + k < n) s += cnt[base + k];
    }
#pragma unroll
    for (int off = 1; off < 64; off <<= 1) s += __shfl_xor(s, off, 64);
    if ((threadIdx.x & 63) == 0) ws[threadIdx.x >> 6] = s;
    __syncthreads();
    if (threadIdx.x == 0) part[blockIdx.x] = ws[0] + ws[1] + ws[2] + ws[3];
}

__global__ void scan_chunks(int* __restrict__ part, int nch, int* __restrict__ rowptr, int n) {
    int l = threadIdx.x;                           // one wave
    int carry = 0;
    for (int base = 0; base < nch; base += 64) {
        int idx = base + l;
        int v = (idx < nch) ? part[idx] : 0;
        int s = v;
#pragma unroll
        for (int off = 1; off < 64; off <<= 1) {
            int u = __shfl_up(s, off, 64);
            if (l >= off) s += u;
        }
        if (idx < nch) part[idx] = s - v + carry;  // exclusive
        carry += __shfl(s, 63, 64);
    }
    if (l == 0) rowptr[n] = carry;
}

__global__ __launch_bounds__(256) void scan_final(const int* __restrict__ cnt,
                                                  const int* __restrict__ part,
                                                  int* __restrict__ rowptr, int n) {
    __shared__ int ws[4];
    int tid = threadIdx.x, l = tid & 63, w = tid >> 6;
    int base = blockIdx.x * 1024 + tid * 4;
    int v[4] = {0, 0, 0, 0};
    if (base + 3 < n) {
        int4 t = *reinterpret_cast<const int4*>(cnt + base);
        v[0] = t.x; v[1] = t.y; v[2] = t.z; v[3] = t.w;
    } else {
#pragma unroll
        for (int k = 0; k < 4; ++k) if (base + k < n) v[k] = cnt[base + k];
    }
    int tsum = v[0] + v[1] + v[2] + v[3];
    int s = tsum;
#pragma unroll
    for (int off = 1; off < 64; off <<= 1) {
        int u = __shfl_up(s, off, 64);
        if (l >= off) s += u;
    }
    if (l == 63) ws[w] = s;
    __syncthreads();
    int woff = 0;
    for (int k = 0; k < w; ++k) woff += ws[k];
    int run = part[blockIdx.x] + woff + s - tsum;
#pragma unroll
    for (int k = 0; k < 4; ++k) {
        int idx = base + k;
        if (idx < n) rowptr[idx] = run;
        run += v[k];
    }
}

// ---------------------------------------------------------------------------
// Deterministic two-level edge multisplit (replaces atomic scatter).
// Coarse bucket = row >> 9 (512 rows). EPB edges per block.
// ---------------------------------------------------------------------------
#define EPB 4096
#define NBMAX 128

// A1: per-block coarse histogram -> H[b*nblk + blk]
__global__ __launch_bounds__(256) void hist_coarse(const int* __restrict__ row,
                                                   int* __restrict__ H, int E, int nblk, int NB) {
    __shared__ int h[NBMAX];
    int tid = threadIdx.x, blk = blockIdx.x;
    for (int b = tid; b < NB; b += 256) h[b] = 0;
    __syncthreads();
    int base = blk * EPB;
    int nloc = min(EPB, E - base);
    for (int k = tid; k < nloc; k += 256) atomicAdd(&h[row[base + k] >> 9], 1);
    __syncthreads();
    for (int b = tid; b < NB; b += 256) H[b * nblk + blk] = h[b];
}

// A2: per-bucket exclusive scan across blocks, + coarse base from rowptr.
__global__ void scan_coarse(int* __restrict__ H, const int* __restrict__ rowptr,
                            int nblk, int N, int NB) {
    int b = blockIdx.x, l = threadIdx.x;
    int r0 = b << 9; if (r0 > N) r0 = N;
    int carry = rowptr[r0];
    for (int s0 = 0; s0 < nblk; s0 += 64) {
        int idx = s0 + l;
        int v = (idx < nblk) ? H[b * nblk + idx] : 0;
        int s = v;
#pragma unroll
        for (int off = 1; off < 64; off <<= 1) {
            int u = __shfl_up(s, off, 64);
            if (l >= off) s += u;
        }
        if (idx < nblk) H[b * nblk + idx] = s - v + carry;
        carry += __shfl(s, 63, 64);
    }
}

// A3: block-local bucket sort in LDS, contiguous per-bucket burst copy out.
__global__ __launch_bounds__(256) void scatter_coarse(const int* __restrict__ row,
                                                      const int* __restrict__ col,
                                                      const int* __restrict__ H,
                                                      unsigned* __restrict__ ebuf,
                                                      int E, int nblk, int NB) {
    __shared__ int h[NBMAX];
    __shared__ int lofs[NBMAX + 1];
    __shared__ int dstv[NBMAX];
    __shared__ unsigned recs[EPB];
    int tid = threadIdx.x, blk = blockIdx.x;
    int base = blk * EPB;
    int nloc = min(EPB, E - base);

    for (int b = tid; b < NB; b += 256) h[b] = 0;
    __syncthreads();
    for (int k = tid; k < nloc; k += 256) atomicAdd(&h[row[base + k] >> 9], 1);
    __syncthreads();
    if (tid == 0) {
        int run = 0;
        for (int b = 0; b < NB; ++b) { lofs[b] = run; run += h[b]; }
        lofs[NB] = run;
    }
    __syncthreads();
    for (int b = tid; b < NB; b += 256) { h[b] = lofs[b]; dstv[b] = H[b * nblk + blk]; }
    __syncthreads();
    for (int k = tid; k < nloc; k += 256) {
        int e = base + k;
        int r = row[e];
        int pos = atomicAdd(&h[r >> 9], 1);
        recs[pos] = ((unsigned)r << 16) | (unsigned)col[e];
    }
    __syncthreads();
    for (int b = 0; b < NB; ++b) {
        int o = lofs[b], cntb = lofs[b + 1] - o, dst = dstv[b];
        for (int k = tid; k < cntb; k += 256) ebuf[dst + k] = recs[o + k];
    }
}

// B: fine scatter within each coarse bucket (block-private 64KB region).
__global__ __launch_bounds__(256) void scatter_fine(const unsigned* __restrict__ ebuf,
                                                    const int* __restrict__ rowptr,
                                                    int* __restrict__ ecol, int N) {
    __shared__ int lcur[512];
    int b = blockIdx.x, tid = threadIdx.x;
    int row0 = b << 9;
    int row1 = min(N, row0 + 512);
    int base = rowptr[row0], endp = rowptr[row1];
    for (int r = tid; r < row1 - row0; r += 256) lcur[r] = rowptr[row0 + r] - base;
    __syncthreads();
    for (int k = base + tid; k < endp; k += 256) {
        unsigned rec = ebuf[k];
        int r = rec >> 16, c = rec & 0xFFFF;
        int rel = atomicAdd(&lcur[r - row0], 1);
        ecol[base + rel] = c;
    }
}

// ---------------------------------------------------------------------------
// Fused sparse attention, one wave per node, depth-4 KV pipeline with a
// clamped column ring. Launched in 4 slices for profiling visibility.
// ---------------------------------------------------------------------------
__global__ __launch_bounds__(256) void attn_fused(
    const unsigned short* __restrict__ QKV,
    const int* __restrict__ rowptr, const int* __restrict__ ecol,
    unsigned short* __restrict__ attn_t, int i0, int i1) {
    int i = i0 + blockIdx.x * 4 + (threadIdx.x >> 6);
    if (i >= i1) return;
    int l = threadIdx.x & 63;

    ushort4 q4 = *reinterpret_cast<const ushort4*>(QKV + (size_t)i * 768 + l * 4);
    float q0 = bf2f(q4.x), q1 = bf2f(q4.y), q2 = bf2f(q4.z), q3 = bf2f(q4.w);

    int j = rowptr[i], end = rowptr[i + 1];
    float z = 0.f, a0 = 0.f, a1 = 0.f, a2 = 0.f, a3 = 0.f;

    if (j < end) {
        int last = end - 1;
#define CL(jj) ecol[(jj) < last ? (jj) : last]
#define KVL(c) (*reinterpret_cast<const u16x8*>(QKV + (size_t)(c) * 768 + 256 + l * 8))
        int cA = CL(j), cB = CL(j + 1), cC = CL(j + 2), cD = CL(j + 3);
        u16x8 kvA = KVL(cA), kvB = KVL(cB), kvC = KVL(cC), kvD = KVL(cD);
        int r0 = CL(j + 4), r1 = CL(j + 5), r2 = CL(j + 6), r3 = CL(j + 7);

#define STEP(KV) { \
        float s = q0 * bf2f(KV[0]) + q1 * bf2f(KV[1]) + q2 * bf2f(KV[2]) + q3 * bf2f(KV[3]); \
        s += __shfl_xor(s, 1, 64); \
        s += __shfl_xor(s, 2, 64); \
        s += __shfl_xor(s, 4, 64); \
        float wgt = __expf(s); \
        z += wgt; \
        a0 += wgt * bf2f(KV[4]); a1 += wgt * bf2f(KV[5]); \
        a2 += wgt * bf2f(KV[6]); a3 += wgt * bf2f(KV[7]); \
        KV = KVL(r0); r0 = r1; r1 = r2; r2 = r3; r3 = CL(j + 8); \
        ++j; }

        while (j < end) {
            STEP(kvA);
            if (j < end) STEP(kvB);
            if (j < end) STEP(kvC);
            if (j < end) STEP(kvD);
        }
#undef STEP
#undef KVL
#undef CL
    }

    float inv = (z > 0.f) ? 1.0f / z : 0.f;
    ushort4 o;
    o.x = f2bf(a0 * inv); o.y = f2bf(a1 * inv);
    o.z = f2bf(a2 * inv); o.w = f2bf(a3 * inv);
    int R = i >> 7, row = i & 127;
    int ks = l >> 4, kb = (l & 15) >> 1, j4 = (l & 1) * 4;
    *reinterpret_cast<ushort4*>(attn_t + (size_t)R * 32768 + ks * 8192 + kb * 1024 + row * 8 + j4) = o;
}

// ---------------------------------------------------------------------------
// Launch
// ---------------------------------------------------------------------------
extern "C" void kernel_launch(void* const* d_in, const int* in_sizes, int n_in,
                              void* d_out, int out_size, void* d_ws, size_t ws_size,
                              hipStream_t stream) {
    const float* x  = (const float*)d_in[0];
    const int*   row = (const int*)d_in[1];
    const int*   col = (const int*)d_in[2];
    const float* Wq = (const float*)d_in[3];
    const float* bq = (const float*)d_in[4];
    const float* Wk = (const float*)d_in[5];
    const float* bk = (const float*)d_in[6];
    const float* Wv = (const float*)d_in[7];
    const float* bv = (const float*)d_in[8];
    const float* Wo = (const float*)d_in[9];
    const float* bo = (const float*)d_in[10];
    int N = in_sizes[0] / DIM;
    int E = in_sizes[1];
    float* out = (float*)d_out;

    int Rtiles = (N + 127) / 128;
    int nch = (N + 1023) / 1024;
    int NB = (N + 511) >> 9;                       // coarse buckets (98)
    int nblk = (E + EPB - 1) / EPB;                // multisplit blocks (391)

    char* p = (char*)d_ws;
    auto alloc = [&](size_t bytes) {
        char* r = p;
        p += (bytes + 255) & ~(size_t)255;
        return r;
    };
    unsigned short* xt     = (unsigned short*)alloc((size_t)Rtiles * 32768 * 2);
    unsigned short* QKV    = (unsigned short*)alloc((size_t)N * 768 * 2);
    unsigned short* attn_t = (unsigned short*)alloc((size_t)Rtiles * 32768 * 2);
    unsigned short* WqkvT  = (unsigned short*)alloc((size_t)768 * DIM * 2);
    unsigned short* WoT    = (unsigned short*)alloc((size_t)DIM * DIM * 2);
    float* bqkv = (float*)alloc(768 * sizeof(float));
    int* cnt    = (int*)alloc((size_t)N * sizeof(int));
    int* part   = (int*)alloc((size_t)nch * sizeof(int));
    int* rowptr = (int*)alloc((size_t)(N + 1) * sizeof(int));
    int* H      = (int*)alloc((size_t)NB * nblk * sizeof(int));
    unsigned* ebuf = (unsigned*)alloc((size_t)E * sizeof(unsigned));
    int* ecol   = (int*)alloc((size_t)E * sizeof(int));

    // fused prep: weights + biases + x conversion
    int prep_items = PREP_W0 + N * 32;
    prep_fused<<<(prep_items + 255) / 256, 256, 0, stream>>>(
        Wq, Wk, Wv, Wo, bq, bk, bv, x, WqkvT, WoT, bqkv, xt, N);

    // CSR rowptr
    hipMemsetAsync(cnt, 0, (size_t)N * sizeof(int), stream);
    hist_rows<<<(E + 255) / 256, 256, 0, stream>>>(row, cnt, E);
    hist_coarse<<<nblk, 256, 0, stream>>>(row, H, E, nblk, NB);
    scan_partial<<<nch, 256, 0, stream>>>(cnt, part, N);
    scan_chunks<<<1, 64, 0, stream>>>(part, nch, rowptr, N);
    scan_final<<<nch, 256, 0, stream>>>(cnt, part, rowptr, N);

    // two-level edge multisplit
    scan_coarse<<<NB, 64, 0, stream>>>(H, rowptr, nblk, N, NB);
    scatter_coarse<<<nblk, 256, 0, stream>>>(row, col, H, ebuf, E, nblk, NB);
    scatter_fine<<<NB, 256, 0, stream>>>(ebuf, rowptr, ecol, N);

    // fused QKV projection -> bf16 records [N][768]
    dim3 g1(Rtiles, 6);
    gemm_tiled<1><<<g1, 256, 0, stream>>>(xt, WqkvT, bqkv, QKV, N, 768);

    // fused sparse attention in 4 slices (per-dispatch profiling visibility)
    int q4n = (N + 3) / 4;
    for (int s4 = 0; s4 < 4; ++s4) {
        int i0 = s4 * q4n;
        int i1 = (s4 == 3) ? N : (s4 + 1) * q4n;
        if (i0 >= i1) continue;
        attn_fused<<<(i1 - i0 + 3) / 4, 256, 0, stream>>>(QKV, rowptr, ecol, attn_t, i0, i1);
    }

    // output projection -> f32 out
    dim3 g2(Rtiles, 2);
    gemm_tiled<0><<<g2, 256, 0, stream>>>(attn_t, WoT, bo, out, N, DIM);
}

// Round 7
// 431.300 us; speedup vs baseline: 2.7564x; 1.1308x over previous
//
#include <hip/hip_runtime.h>
#include <hip/hip_bf16.h>

#define DIM 256
#define NH 8

typedef __attribute__((ext_vector_type(4))) float f32x4;
typedef __attribute__((ext_vector_type(8))) short bf16x8;
typedef __attribute__((ext_vector_type(8))) unsigned short u16x8;

__device__ __forceinline__ float bf2f(unsigned short u) {
    union { unsigned int i; float f; } x; x.i = ((unsigned int)u) << 16; return x.f;
}
__device__ __forceinline__ unsigned short f2bf(float f) {
    union { float f; unsigned int i; } x; x.f = f;
    unsigned int r = x.i + 0x7fffu + ((x.i >> 16) & 1u);
    return (unsigned short)(r >> 16);
}

// ---------------------------------------------------------------------------
// Layouts.
// QKV record per node (768 bf16): [0..255]=Q head-contig, [256..767]=KV
// lane-interleaved (lane l owns {k[4l..4l+3], v[4l..4l+3]} = 16B).
// Tiled GEMM operand layout: off(R,ks,kb,row,j)=R*32768+ks*8192+kb*1024+row*8+j
// == the LDS layout: staging is a contiguous copy; ds_read_b128 conflict-free.
// Edge sort: coarse buckets of 512 rows; packed edge record = (row<<16)|col.
// CSR derived entirely from the multisplit (no global atomic histogram).
// ---------------------------------------------------------------------------
__device__ __forceinline__ void map_col(int o, int& which, int& c) {
    int cp;
    if (o < 256) { which = 0; cp = o; }
    else {
        int u = o - 256;
        int lane = u >> 3, slot = u & 7;
        which = (slot < 4) ? 1 : 2;
        cp = lane * 4 + (slot & 3);
    }
    c = (cp & 31) * 8 + (cp >> 5);   // reference reshape: c = d*NH + h
}

// Fused prep: WqkvT (tiled), WoT (tiled), bqkv, and x -> tiled bf16.
#define PREP_W0 262912
__global__ void prep_fused(const float* __restrict__ Wq, const float* __restrict__ Wk,
                           const float* __restrict__ Wv, const float* __restrict__ Wo,
                           const float* __restrict__ bq, const float* __restrict__ bk,
                           const float* __restrict__ bv, const float* __restrict__ x,
                           unsigned short* __restrict__ WqkvT,
                           unsigned short* __restrict__ WoT,
                           float* __restrict__ bqkv,
                           unsigned short* __restrict__ xt, int M) {
    int idx = blockIdx.x * 256 + threadIdx.x;
    if (idx < 768 * 256) {
        int CB = idx >> 15;
        int rem = idx & 32767;
        int ks = rem >> 13, kb = (rem >> 10) & 7, ci = (rem >> 3) & 127, jj = rem & 7;
        int o = CB * 128 + ci;
        int k = ks * 64 + kb * 8 + jj;
        int which, c; map_col(o, which, c);
        const float* W = (which == 0) ? Wq : (which == 1 ? Wk : Wv);
        float scale = (which == 0) ? 0.17677669529663687f : 1.0f;
        WqkvT[idx] = f2bf(W[k * DIM + c] * scale);
    } else if (idx < 768 * 256 + 256 * 256) {
        int id2 = idx - 768 * 256;
        int CB = id2 >> 15;
        int rem = id2 & 32767;
        int ks = rem >> 13, kb = (rem >> 10) & 7, ci = (rem >> 3) & 127, jj = rem & 7;
        int o = CB * 128 + ci;
        int cp = ks * 64 + kb * 8 + jj;
        WoT[id2] = f2bf(Wo[((cp & 31) * 8 + (cp >> 5)) * DIM + o]);
    } else if (idx < PREP_W0) {
        int o = idx - (768 * 256 + 256 * 256);
        if (o < 768) {
            int which, c; map_col(o, which, c);
            const float* b = (which == 0) ? bq : (which == 1 ? bk : bv);
            float scale = (which == 0) ? 0.17677669529663687f : 1.0f;
            bqkv[o] = b[c] * scale;
        }
    } else {
        int t = idx - PREP_W0;
        int r = t >> 5;
        if (r >= M) return;
        int kc = (t & 31) * 8;
        float4 v0 = *reinterpret_cast<const float4*>(x + (size_t)r * DIM + kc);
        float4 v1 = *reinterpret_cast<const float4*>(x + (size_t)r * DIM + kc + 4);
        u16x8 o;
        o[0] = f2bf(v0.x); o[1] = f2bf(v0.y); o[2] = f2bf(v0.z); o[3] = f2bf(v0.w);
        o[4] = f2bf(v1.x); o[5] = f2bf(v1.y); o[6] = f2bf(v1.z); o[7] = f2bf(v1.w);
        int R = r >> 7, row = r & 127, ks = kc >> 6, kb = (kc & 63) >> 3;
        *reinterpret_cast<u16x8*>(xt + (size_t)R * 32768 + ks * 8192 + kb * 1024 + row * 8) = o;
    }
}

// ---------------------------------------------------------------------------
// LDS-staged MFMA GEMM. 128x128 tile, 4 waves, BK=64, 32KB LDS.
// 1-D grid, column-tile fastest-varying: the CT col-tiles sharing one A
// row-tile are temporally adjacent -> A fetched from HBM once.
// ---------------------------------------------------------------------------
#define GLOAD_LDS16(gp, lp) \
    __builtin_amdgcn_global_load_lds( \
        (const __attribute__((address_space(1))) unsigned int*)(gp), \
        (__attribute__((address_space(3))) unsigned int*)(lp), 16, 0, 0)

template<int OUT_BF16, int CT>
__global__ __launch_bounds__(256) void gemm_tiled(
    const unsigned short* __restrict__ At, const unsigned short* __restrict__ Bt,
    const float* __restrict__ bias, void* __restrict__ Cout, int M, int ldc) {
    __shared__ unsigned short lds[16384];          // A 16KB @0, B 16KB @8192
    int tid = threadIdx.x;
    int l = tid & 63, w = tid >> 6;
    int xtile = blockIdx.x / CT, ctile = blockIdx.x % CT;
    const unsigned short* Abase = At + (size_t)xtile * 32768;
    const unsigned short* Bbase = Bt + (size_t)ctile * 32768;

    int rbase = (w >> 1) * 64 + (l & 15);
    int cbase = (w & 1) * 64 + (l & 15);
    int kq = l >> 4;

    f32x4 acc[4][4] = {};
#pragma unroll
    for (int ks = 0; ks < 4; ++ks) {
        if (ks) __syncthreads();
#pragma unroll
        for (int i = 0; i < 4; ++i) {
            GLOAD_LDS16(Abase + (size_t)ks * 8192 + i * 2048 + tid * 8, &lds[i * 2048 + tid * 8]);
            GLOAD_LDS16(Bbase + (size_t)ks * 8192 + i * 2048 + tid * 8, &lds[8192 + i * 2048 + tid * 8]);
        }
        __syncthreads();
#pragma unroll
        for (int kk = 0; kk < 2; ++kk) {
            int kb = kk * 4 + kq;
            bf16x8 a[4], b[4];
#pragma unroll
            for (int m = 0; m < 4; ++m)
                a[m] = *reinterpret_cast<const bf16x8*>(&lds[kb * 1024 + (rbase + m * 16) * 8]);
#pragma unroll
            for (int n = 0; n < 4; ++n)
                b[n] = *reinterpret_cast<const bf16x8*>(&lds[8192 + kb * 1024 + (cbase + n * 16) * 8]);
#pragma unroll
            for (int m = 0; m < 4; ++m)
#pragma unroll
                for (int n = 0; n < 4; ++n)
                    acc[m][n] = __builtin_amdgcn_mfma_f32_16x16x32_bf16(a[m], b[n], acc[m][n], 0, 0, 0);
        }
    }

    int row0 = xtile * 128 + (w >> 1) * 64;
    int col0 = ctile * 128 + (w & 1) * 64;
    int rb = (l >> 4) * 4, cc = l & 15;
#pragma unroll
    for (int n = 0; n < 4; ++n) {
        int c = col0 + n * 16 + cc;
        float bv = bias[c];
#pragma unroll
        for (int m = 0; m < 4; ++m) {
#pragma unroll
            for (int j = 0; j < 4; ++j) {
                int r = row0 + m * 16 + rb + j;
                if (r < M) {
                    float v = acc[m][n][j] + bv;
                    if (OUT_BF16) ((unsigned short*)Cout)[(size_t)r * ldc + c] = f2bf(v);
                    else          ((float*)Cout)[(size_t)r * ldc + c] = v;
                }
            }
        }
    }
}

// ---------------------------------------------------------------------------
// Edge multisplit + CSR, all derived from per-block coarse histograms.
// ---------------------------------------------------------------------------
#define EPB 4096
#define NBMAX 128

// A1: per-block coarse histogram -> H[b*nblk + blk]
__global__ __launch_bounds__(256) void hist_coarse(const int* __restrict__ row,
                                                   int* __restrict__ H, int E, int nblk, int NB) {
    __shared__ int h[NBMAX];
    int tid = threadIdx.x, blk = blockIdx.x;
    for (int b = tid; b < NB; b += 256) h[b] = 0;
    __syncthreads();
    int base = blk * EPB;
    int nloc = min(EPB, E - base);
    for (int k = tid; k < nloc; k += 256) atomicAdd(&h[row[base + k] >> 9], 1);
    __syncthreads();
    for (int b = tid; b < NB; b += 256) H[b * nblk + blk] = h[b];
}

// totals per coarse bucket
__global__ __launch_bounds__(256) void bucket_totals(const int* __restrict__ H,
                                                     int* __restrict__ Tb, int nblk) {
    __shared__ int ws[4];
    int b = blockIdx.x, tid = threadIdx.x;
    int s = 0;
    for (int k = tid; k < nblk; k += 256) s += H[b * nblk + k];
#pragma unroll
    for (int off = 1; off < 64; off <<= 1) s += __shfl_xor(s, off, 64);
    if ((tid & 63) == 0) ws[tid >> 6] = s;
    __syncthreads();
    if (tid == 0) Tb[b] = ws[0] + ws[1] + ws[2] + ws[3];
}

// exclusive scan of bucket totals -> Cbase[0..NB]; also rowptr[N] = E
__global__ void scan_buckets(const int* __restrict__ Tb, int* __restrict__ Cbase,
                             int NB, int* __restrict__ rowptr, int N) {
    int l = threadIdx.x;
    int carry = 0;
    for (int base = 0; base < NB; base += 64) {
        int idx = base + l;
        int v = (idx < NB) ? Tb[idx] : 0;
        int s = v;
#pragma unroll
        for (int off = 1; off < 64; off <<= 1) {
            int u = __shfl_up(s, off, 64);
            if (l >= off) s += u;
        }
        if (idx < NB) Cbase[idx] = s - v + carry;
        carry += __shfl(s, 63, 64);
    }
    if (l == 0) { Cbase[NB] = carry; rowptr[N] = carry; }
}

// A2: per-bucket exclusive scan across blocks, base = Cbase[b]
__global__ void scan_coarse(int* __restrict__ H, const int* __restrict__ Cbase, int nblk) {
    int b = blockIdx.x, l = threadIdx.x;
    int carry = Cbase[b];
    for (int s0 = 0; s0 < nblk; s0 += 64) {
        int idx = s0 + l;
        int v = (idx < nblk) ? H[b * nblk + idx] : 0;
        int s = v;
#pragma unroll
        for (int off = 1; off < 64; off <<= 1) {
            int u = __shfl_up(s, off, 64);
            if (l >= off) s += u;
        }
        if (idx < nblk) H[b * nblk + idx] = s - v + carry;
        carry += __shfl(s, 63, 64);
    }
}

// A3: block-local bucket sort in LDS, contiguous per-bucket burst copy out.
__global__ __launch_bounds__(256) void scatter_coarse(const int* __restrict__ row,
                                                      const int* __restrict__ col,
                                                      const int* __restrict__ H,
                                                      unsigned* __restrict__ ebuf,
                                                      int E, int nblk, int NB) {
    __shared__ int h[NBMAX];
    __shared__ int lofs[NBMAX + 1];
    __shared__ int dstv[NBMAX];
    __shared__ unsigned recs[EPB];
    int tid = threadIdx.x, blk = blockIdx.x;
    int base = blk * EPB;
    int nloc = min(EPB, E - base);

    for (int b = tid; b < NB; b += 256) h[b] = 0;
    __syncthreads();
    for (int k = tid; k < nloc; k += 256) atomicAdd(&h[row[base + k] >> 9], 1);
    __syncthreads();
    if (tid == 0) {
        int run = 0;
        for (int b = 0; b < NB; ++b) { lofs[b] = run; run += h[b]; }
        lofs[NB] = run;
    }
    __syncthreads();
    for (int b = tid; b < NB; b += 256) { h[b] = lofs[b]; dstv[b] = H[b * nblk + blk]; }
    __syncthreads();
    for (int k = tid; k < nloc; k += 256) {
        int e = base + k;
        int r = row[e];
        int pos = atomicAdd(&h[r >> 9], 1);
        recs[pos] = ((unsigned)r << 16) | (unsigned)col[e];
    }
    __syncthreads();
    for (int b = 0; b < NB; ++b) {
        int o = lofs[b], cntb = lofs[b + 1] - o, dst = dstv[b];
        for (int k = tid; k < cntb; k += 256) ebuf[dst + k] = recs[o + k];
    }
}

// B: fused fine pass per coarse bucket: LDS histogram of 512 rows -> block
// scan -> write rowptr span -> scatter cols within the bucket's private span.
__global__ __launch_bounds__(256) void fine_fused(const unsigned* __restrict__ ebuf,
                                                  const int* __restrict__ Cbase,
                                                  int* __restrict__ rowptr,
                                                  int* __restrict__ ecol, int N) {
    __shared__ int lcnt[512];
    __shared__ int lcur[512];
    __shared__ int ws[4];
    int b = blockIdx.x, tid = threadIdx.x, l = tid & 63, w = tid >> 6;
    int row0 = b << 9;
    int nr = min(512, N - row0);
    int base = Cbase[b], endp = Cbase[b + 1];

    lcnt[tid] = 0; lcnt[tid + 256] = 0;
    __syncthreads();
    for (int k = base + tid; k < endp; k += 256)
        atomicAdd(&lcnt[(ebuf[k] >> 16) - row0], 1);
    __syncthreads();

    int c0 = lcnt[2 * tid], c1 = lcnt[2 * tid + 1];
    int ps = c0 + c1;
    int s = ps;
#pragma unroll
    for (int off = 1; off < 64; off <<= 1) {
        int u = __shfl_up(s, off, 64);
        if (l >= off) s += u;
    }
    if (l == 63) ws[w] = s;
    __syncthreads();
    int woff = 0;
    for (int k = 0; k < w; ++k) woff += ws[k];
    int excl = woff + s - ps;                      // pair-exclusive prefix
    if (2 * tid < nr)     rowptr[row0 + 2 * tid]     = base + excl;
    if (2 * tid + 1 < nr) rowptr[row0 + 2 * tid + 1] = base + excl + c0;
    lcur[2 * tid] = excl;
    lcur[2 * tid + 1] = excl + c0;
    __syncthreads();

    for (int k = base + tid; k < endp; k += 256) {
        unsigned rec = ebuf[k];
        int r = (rec >> 16) - row0, c = rec & 0xFFFF;
        int rel = atomicAdd(&lcur[r], 1);
        ecol[base + rel] = c;
    }
}

// ---------------------------------------------------------------------------
// Fused sparse attention, one wave per node, depth-4 KV pipeline with a
// clamped column ring. Launched in 4 slices for profiling visibility.
// ---------------------------------------------------------------------------
__global__ __launch_bounds__(256) void attn_fused(
    const unsigned short* __restrict__ QKV,
    const int* __restrict__ rowptr, const int* __restrict__ ecol,
    unsigned short* __restrict__ attn_t, int i0, int i1) {
    int i = i0 + blockIdx.x * 4 + (threadIdx.x >> 6);
    if (i >= i1) return;
    int l = threadIdx.x & 63;

    ushort4 q4 = *reinterpret_cast<const ushort4*>(QKV + (size_t)i * 768 + l * 4);
    float q0 = bf2f(q4.x), q1 = bf2f(q4.y), q2 = bf2f(q4.z), q3 = bf2f(q4.w);

    int j = rowptr[i], end = rowptr[i + 1];
    float z = 0.f, a0 = 0.f, a1 = 0.f, a2 = 0.f, a3 = 0.f;

    if (j < end) {
        int last = end - 1;
#define CL(jj) ecol[(jj) < last ? (jj) : last]
#define KVL(c) (*reinterpret_cast<const u16x8*>(QKV + (size_t)(c) * 768 + 256 + l * 8))
        int cA = CL(j), cB = CL(j + 1), cC = CL(j + 2), cD = CL(j + 3);
        u16x8 kvA = KVL(cA), kvB = KVL(cB), kvC = KVL(cC), kvD = KVL(cD);
        int r0 = CL(j + 4), r1 = CL(j + 5), r2 = CL(j + 6), r3 = CL(j + 7);

#define STEP(KV) { \
        float s = q0 * bf2f(KV[0]) + q1 * bf2f(KV[1]) + q2 * bf2f(KV[2]) + q3 * bf2f(KV[3]); \
        s += __shfl_xor(s, 1, 64); \
        s += __shfl_xor(s, 2, 64); \
        s += __shfl_xor(s, 4, 64); \
        float wgt = __expf(s); \
        z += wgt; \
        a0 += wgt * bf2f(KV[4]); a1 += wgt * bf2f(KV[5]); \
        a2 += wgt * bf2f(KV[6]); a3 += wgt * bf2f(KV[7]); \
        KV = KVL(r0); r0 = r1; r1 = r2; r2 = r3; r3 = CL(j + 8); \
        ++j; }

        while (j < end) {
            STEP(kvA);
            if (j < end) STEP(kvB);
            if (j < end) STEP(kvC);
            if (j < end) STEP(kvD);
        }
#undef STEP
#undef KVL
#undef CL
    }

    float inv = (z > 0.f) ? 1.0f / z : 0.f;
    ushort4 o;
    o.x = f2bf(a0 * inv); o.y = f2bf(a1 * inv);
    o.z = f2bf(a2 * inv); o.w = f2bf(a3 * inv);
    int R = i >> 7, row = i & 127;
    int ks = l >> 4, kb = (l & 15) >> 1, j4 = (l & 1) * 4;
    *reinterpret_cast<ushort4*>(attn_t + (size_t)R * 32768 + ks * 8192 + kb * 1024 + row * 8 + j4) = o;
}

// ---------------------------------------------------------------------------
// Launch
// ---------------------------------------------------------------------------
extern "C" void kernel_launch(void* const* d_in, const int* in_sizes, int n_in,
                              void* d_out, int out_size, void* d_ws, size_t ws_size,
                              hipStream_t stream) {
    const float* x  = (const float*)d_in[0];
    const int*   row = (const int*)d_in[1];
    const int*   col = (const int*)d_in[2];
    const float* Wq = (const float*)d_in[3];
    const float* bq = (const float*)d_in[4];
    const float* Wk = (const float*)d_in[5];
    const float* bk = (const float*)d_in[6];
    const float* Wv = (const float*)d_in[7];
    const float* bv = (const float*)d_in[8];
    const float* Wo = (const float*)d_in[9];
    const float* bo = (const float*)d_in[10];
    int N = in_sizes[0] / DIM;
    int E = in_sizes[1];
    float* out = (float*)d_out;

    int Rtiles = (N + 127) / 128;
    int NB = (N + 511) >> 9;                       // coarse buckets (98)
    int nblk = (E + EPB - 1) / EPB;                // multisplit blocks (391)

    char* p = (char*)d_ws;
    auto alloc = [&](size_t bytes) {
        char* r = p;
        p += (bytes + 255) & ~(size_t)255;
        return r;
    };
    unsigned short* xt     = (unsigned short*)alloc((size_t)Rtiles * 32768 * 2);
    unsigned short* QKV    = (unsigned short*)alloc((size_t)N * 768 * 2);
    unsigned short* attn_t = (unsigned short*)alloc((size_t)Rtiles * 32768 * 2);
    unsigned short* WqkvT  = (unsigned short*)alloc((size_t)768 * DIM * 2);
    unsigned short* WoT    = (unsigned short*)alloc((size_t)DIM * DIM * 2);
    float* bqkv = (float*)alloc(768 * sizeof(float));
    int* rowptr = (int*)alloc((size_t)(N + 1) * sizeof(int));
    int* H      = (int*)alloc((size_t)NB * nblk * sizeof(int));
    int* Tb     = (int*)alloc((size_t)NB * sizeof(int));
    int* Cbase  = (int*)alloc((size_t)(NB + 1) * sizeof(int));
    unsigned* ebuf = (unsigned*)alloc((size_t)E * sizeof(unsigned));
    int* ecol   = (int*)alloc((size_t)E * sizeof(int));

    // fused prep: weights + biases + x conversion
    int prep_items = PREP_W0 + N * 32;
    prep_fused<<<(prep_items + 255) / 256, 256, 0, stream>>>(
        Wq, Wk, Wv, Wo, bq, bk, bv, x, WqkvT, WoT, bqkv, xt, N);

    // multisplit-derived CSR
    hist_coarse<<<nblk, 256, 0, stream>>>(row, H, E, nblk, NB);
    bucket_totals<<<NB, 256, 0, stream>>>(H, Tb, nblk);
    scan_buckets<<<1, 64, 0, stream>>>(Tb, Cbase, NB, rowptr, N);
    scan_coarse<<<NB, 64, 0, stream>>>(H, Cbase, nblk);
    scatter_coarse<<<nblk, 256, 0, stream>>>(row, col, H, ebuf, E, nblk, NB);
    fine_fused<<<NB, 256, 0, stream>>>(ebuf, Cbase, rowptr, ecol, N);

    // fused QKV projection -> bf16 records [N][768]  (col-tile fastest)
    gemm_tiled<1, 6><<<Rtiles * 6, 256, 0, stream>>>(xt, WqkvT, bqkv, QKV, N, 768);

    // fused sparse attention in 4 slices (per-dispatch profiling visibility)
    int q4n = (N + 3) / 4;
    for (int s4 = 0; s4 < 4; ++s4) {
        int i0 = s4 * q4n;
        int i1 = (s4 == 3) ? N : (s4 + 1) * q4n;
        if (i0 >= i1) continue;
        attn_fused<<<(i1 - i0 + 3) / 4, 256, 0, stream>>>(QKV, rowptr, ecol, attn_t, i0, i1);
    }

    // output projection -> f32 out
    gemm_tiled<0, 2><<<Rtiles * 2, 256, 0, stream>>>(attn_t, WoT, bo, out, N, DIM);
}

// Round 8
// 416.474 us; speedup vs baseline: 2.8545x; 1.0356x over previous
//
#include <hip/hip_runtime.h>
#include <hip/hip_bf16.h>

#define DIM 256
#define NH 8

typedef __attribute__((ext_vector_type(4))) float f32x4;
typedef __attribute__((ext_vector_type(8))) short bf16x8;
typedef __attribute__((ext_vector_type(8))) unsigned short u16x8;

__device__ __forceinline__ float bf2f(unsigned short u) {
    union { unsigned int i; float f; } x; x.i = ((unsigned int)u) << 16; return x.f;
}
__device__ __forceinline__ unsigned short f2bf(float f) {
    union { float f; unsigned int i; } x; x.f = f;
    unsigned int r = x.i + 0x7fffu + ((x.i >> 16) & 1u);
    return (unsigned short)(r >> 16);
}

// ---------------------------------------------------------------------------
// Layouts.
// QKV record per node (768 bf16): [0..255]=Q head-contig, [256..767]=KV
// lane-interleaved (lane l owns {k[4l..4l+3], v[4l..4l+3]} = 16B).
// Tiled GEMM operand layout: off(R,ks,kb,row,j)=R*32768+ks*8192+kb*1024+row*8+j
// == the LDS layout: staging is a contiguous copy; ds_read_b128 conflict-free.
// Edge sort: coarse buckets of 512 rows; packed edge record = (row<<16)|col.
// CSR derived entirely from the multisplit (no global atomic histogram).
// ---------------------------------------------------------------------------
__device__ __forceinline__ void map_col(int o, int& which, int& c) {
    int cp;
    if (o < 256) { which = 0; cp = o; }
    else {
        int u = o - 256;
        int lane = u >> 3, slot = u & 7;
        which = (slot < 4) ? 1 : 2;
        cp = lane * 4 + (slot & 3);
    }
    c = (cp & 31) * 8 + (cp >> 5);   // reference reshape: c = d*NH + h
}

// Fused prep: WqkvT (tiled), WoT (tiled), bqkv, and x -> tiled bf16.
#define PREP_W0 262912
__global__ void prep_fused(const float* __restrict__ Wq, const float* __restrict__ Wk,
                           const float* __restrict__ Wv, const float* __restrict__ Wo,
                           const float* __restrict__ bq, const float* __restrict__ bk,
                           const float* __restrict__ bv, const float* __restrict__ x,
                           unsigned short* __restrict__ WqkvT,
                           unsigned short* __restrict__ WoT,
                           float* __restrict__ bqkv,
                           unsigned short* __restrict__ xt, int M) {
    int idx = blockIdx.x * 256 + threadIdx.x;
    if (idx < 768 * 256) {
        int CB = idx >> 15;
        int rem = idx & 32767;
        int ks = rem >> 13, kb = (rem >> 10) & 7, ci = (rem >> 3) & 127, jj = rem & 7;
        int o = CB * 128 + ci;
        int k = ks * 64 + kb * 8 + jj;
        int which, c; map_col(o, which, c);
        const float* W = (which == 0) ? Wq : (which == 1 ? Wk : Wv);
        float scale = (which == 0) ? 0.17677669529663687f : 1.0f;
        WqkvT[idx] = f2bf(W[k * DIM + c] * scale);
    } else if (idx < 768 * 256 + 256 * 256) {
        int id2 = idx - 768 * 256;
        int CB = id2 >> 15;
        int rem = id2 & 32767;
        int ks = rem >> 13, kb = (rem >> 10) & 7, ci = (rem >> 3) & 127, jj = rem & 7;
        int o = CB * 128 + ci;
        int cp = ks * 64 + kb * 8 + jj;
        WoT[id2] = f2bf(Wo[((cp & 31) * 8 + (cp >> 5)) * DIM + o]);
    } else if (idx < PREP_W0) {
        int o = idx - (768 * 256 + 256 * 256);
        if (o < 768) {
            int which, c; map_col(o, which, c);
            const float* b = (which == 0) ? bq : (which == 1 ? bk : bv);
            float scale = (which == 0) ? 0.17677669529663687f : 1.0f;
            bqkv[o] = b[c] * scale;
        }
    } else {
        int t = idx - PREP_W0;
        int r = t >> 5;
        if (r >= M) return;
        int kc = (t & 31) * 8;
        float4 v0 = *reinterpret_cast<const float4*>(x + (size_t)r * DIM + kc);
        float4 v1 = *reinterpret_cast<const float4*>(x + (size_t)r * DIM + kc + 4);
        u16x8 o;
        o[0] = f2bf(v0.x); o[1] = f2bf(v0.y); o[2] = f2bf(v0.z); o[3] = f2bf(v0.w);
        o[4] = f2bf(v1.x); o[5] = f2bf(v1.y); o[6] = f2bf(v1.z); o[7] = f2bf(v1.w);
        int R = r >> 7, row = r & 127, ks = kc >> 6, kb = (kc & 63) >> 3;
        *reinterpret_cast<u16x8*>(xt + (size_t)R * 32768 + ks * 8192 + kb * 1024 + row * 8) = o;
    }
}

// ---------------------------------------------------------------------------
// LDS-staged MFMA GEMM. 128x128 tile, 4 waves, BK=64, 32KB LDS.
// Bijective XCD swizzle (m204): XCD k owns a contiguous logical tile range,
// so the CT col-tiles sharing one A row-tile hit the SAME per-XCD L2.
// ---------------------------------------------------------------------------
#define GLOAD_LDS16(gp, lp) \
    __builtin_amdgcn_global_load_lds( \
        (const __attribute__((address_space(1))) unsigned int*)(gp), \
        (__attribute__((address_space(3))) unsigned int*)(lp), 16, 0, 0)

template<int OUT_BF16, int CT>
__global__ __launch_bounds__(256) void gemm_tiled(
    const unsigned short* __restrict__ At, const unsigned short* __restrict__ Bt,
    const float* __restrict__ bias, void* __restrict__ Cout, int M, int ldc) {
    __shared__ unsigned short lds[16384];          // A 16KB @0, B 16KB @8192
    int tid = threadIdx.x;
    int l = tid & 63, w = tid >> 6;

    // bijective XCD swizzle: orig%8 = physical XCD (round-robin dispatch)
    int nwg = gridDim.x;
    int q = nwg >> 3, r8 = nwg & 7;
    int xcd = blockIdx.x & 7, pos = blockIdx.x >> 3;
    int wg = (xcd < r8 ? xcd * (q + 1) : r8 * (q + 1) + (xcd - r8) * q) + pos;
    int xtile = wg / CT, ctile = wg % CT;

    const unsigned short* Abase = At + (size_t)xtile * 32768;
    const unsigned short* Bbase = Bt + (size_t)ctile * 32768;

    int rbase = (w >> 1) * 64 + (l & 15);
    int cbase = (w & 1) * 64 + (l & 15);
    int kq = l >> 4;

    f32x4 acc[4][4] = {};
#pragma unroll
    for (int ks = 0; ks < 4; ++ks) {
        if (ks) __syncthreads();
#pragma unroll
        for (int i = 0; i < 4; ++i) {
            GLOAD_LDS16(Abase + (size_t)ks * 8192 + i * 2048 + tid * 8, &lds[i * 2048 + tid * 8]);
            GLOAD_LDS16(Bbase + (size_t)ks * 8192 + i * 2048 + tid * 8, &lds[8192 + i * 2048 + tid * 8]);
        }
        __syncthreads();
#pragma unroll
        for (int kk = 0; kk < 2; ++kk) {
            int kb = kk * 4 + kq;
            bf16x8 a[4], b[4];
#pragma unroll
            for (int m = 0; m < 4; ++m)
                a[m] = *reinterpret_cast<const bf16x8*>(&lds[kb * 1024 + (rbase + m * 16) * 8]);
#pragma unroll
            for (int n = 0; n < 4; ++n)
                b[n] = *reinterpret_cast<const bf16x8*>(&lds[8192 + kb * 1024 + (cbase + n * 16) * 8]);
#pragma unroll
            for (int m = 0; m < 4; ++m)
#pragma unroll
                for (int n = 0; n < 4; ++n)
                    acc[m][n] = __builtin_amdgcn_mfma_f32_16x16x32_bf16(a[m], b[n], acc[m][n], 0, 0, 0);
        }
    }

    int row0 = xtile * 128 + (w >> 1) * 64;
    int col0 = ctile * 128 + (w & 1) * 64;
    int rb = (l >> 4) * 4, cc = l & 15;
#pragma unroll
    for (int n = 0; n < 4; ++n) {
        int c = col0 + n * 16 + cc;
        float bv = bias[c];
#pragma unroll
        for (int m = 0; m < 4; ++m) {
#pragma unroll
            for (int j = 0; j < 4; ++j) {
                int r = row0 + m * 16 + rb + j;
                if (r < M) {
                    float v = acc[m][n][j] + bv;
                    if (OUT_BF16) ((unsigned short*)Cout)[(size_t)r * ldc + c] = f2bf(v);
                    else          ((float*)Cout)[(size_t)r * ldc + c] = v;
                }
            }
        }
    }
}

// ---------------------------------------------------------------------------
// Edge multisplit + CSR, all derived from per-block coarse histograms.
// ---------------------------------------------------------------------------
#define EPB 4096
#define NBMAX 128

// A1: per-block coarse histogram -> H[b*nblk + blk]
__global__ __launch_bounds__(256) void hist_coarse(const int* __restrict__ row,
                                                   int* __restrict__ H, int E, int nblk, int NB) {
    __shared__ int h[NBMAX];
    int tid = threadIdx.x, blk = blockIdx.x;
    for (int b = tid; b < NB; b += 256) h[b] = 0;
    __syncthreads();
    int base = blk * EPB;
    int nloc = min(EPB, E - base);
    for (int k = tid; k < nloc; k += 256) atomicAdd(&h[row[base + k] >> 9], 1);
    __syncthreads();
    for (int b = tid; b < NB; b += 256) H[b * nblk + blk] = h[b];
}

// totals per coarse bucket
__global__ __launch_bounds__(256) void bucket_totals(const int* __restrict__ H,
                                                     int* __restrict__ Tb, int nblk) {
    __shared__ int ws[4];
    int b = blockIdx.x, tid = threadIdx.x;
    int s = 0;
    for (int k = tid; k < nblk; k += 256) s += H[b * nblk + k];
#pragma unroll
    for (int off = 1; off < 64; off <<= 1) s += __shfl_xor(s, off, 64);
    if ((tid & 63) == 0) ws[tid >> 6] = s;
    __syncthreads();
    if (tid == 0) Tb[b] = ws[0] + ws[1] + ws[2] + ws[3];
}

// exclusive scan of bucket totals -> Cbase[0..NB]; also rowptr[N] = E
__global__ void scan_buckets(const int* __restrict__ Tb, int* __restrict__ Cbase,
                             int NB, int* __restrict__ rowptr, int N) {
    int l = threadIdx.x;
    int carry = 0;
    for (int base = 0; base < NB; base += 64) {
        int idx = base + l;
        int v = (idx < NB) ? Tb[idx] : 0;
        int s = v;
#pragma unroll
        for (int off = 1; off < 64; off <<= 1) {
            int u = __shfl_up(s, off, 64);
            if (l >= off) s += u;
        }
        if (idx < NB) Cbase[idx] = s - v + carry;
        carry += __shfl(s, 63, 64);
    }
    if (l == 0) { Cbase[NB] = carry; rowptr[N] = carry; }
}

// A2: per-bucket exclusive scan across blocks, base = Cbase[b]
__global__ void scan_coarse(int* __restrict__ H, const int* __restrict__ Cbase, int nblk) {
    int b = blockIdx.x, l = threadIdx.x;
    int carry = Cbase[b];
    for (int s0 = 0; s0 < nblk; s0 += 64) {
        int idx = s0 + l;
        int v = (idx < nblk) ? H[b * nblk + idx] : 0;
        int s = v;
#pragma unroll
        for (int off = 1; off < 64; off <<= 1) {
            int u = __shfl_up(s, off, 64);
            if (l >= off) s += u;
        }
        if (idx < nblk) H[b * nblk + idx] = s - v + carry;
        carry += __shfl(s, 63, 64);
    }
}

// A3: block-local bucket sort. Single global read: records packed into LDS
// during the histogram pass; scatter is LDS->LDS; copy-out is burst-coalesced.
__global__ __launch_bounds__(256) void scatter_coarse(const int* __restrict__ row,
                                                      const int* __restrict__ col,
                                                      const int* __restrict__ H,
                                                      unsigned* __restrict__ ebuf,
                                                      int E, int nblk, int NB) {
    __shared__ int h[NBMAX];
    __shared__ int lofs[NBMAX + 1];
    __shared__ int dstv[NBMAX];
    __shared__ unsigned rin[EPB];
    __shared__ unsigned rsort[EPB];
    int tid = threadIdx.x, blk = blockIdx.x;
    int base = blk * EPB;
    int nloc = min(EPB, E - base);

    for (int b = tid; b < NB; b += 256) h[b] = 0;
    __syncthreads();
    for (int k = tid; k < nloc; k += 256) {
        int r = row[base + k], c = col[base + k];
        rin[k] = ((unsigned)r << 16) | (unsigned)c;
        atomicAdd(&h[r >> 9], 1);
    }
    __syncthreads();
    if (tid == 0) {
        int run = 0;
        for (int b = 0; b < NB; ++b) { lofs[b] = run; run += h[b]; }
        lofs[NB] = run;
    }
    __syncthreads();
    for (int b = tid; b < NB; b += 256) { h[b] = lofs[b]; dstv[b] = H[b * nblk + blk]; }
    __syncthreads();
    for (int k = tid; k < nloc; k += 256) {
        unsigned rec = rin[k];
        int pos = atomicAdd(&h[rec >> 25], 1);     // rec>>25 == (r>>9) since r = rec>>16
        rsort[pos] = rec;
    }
    __syncthreads();
    for (int b = 0; b < NB; ++b) {
        int o = lofs[b], cntb = lofs[b + 1] - o, dst = dstv[b];
        for (int k = tid; k < cntb; k += 256) ebuf[dst + k] = rsort[o + k];
    }
}

// B: fused fine pass per coarse bucket: LDS histogram of 512 rows -> block
// scan -> write rowptr span -> scatter cols within the bucket's private span.
__global__ __launch_bounds__(256) void fine_fused(const unsigned* __restrict__ ebuf,
                                                  const int* __restrict__ Cbase,
                                                  int* __restrict__ rowptr,
                                                  int* __restrict__ ecol, int N) {
    __shared__ int lcnt[512];
    __shared__ int lcur[512];
    __shared__ int ws[4];
    int b = blockIdx.x, tid = threadIdx.x, l = tid & 63, w = tid >> 6;
    int row0 = b << 9;
    int nr = min(512, N - row0);
    int base = Cbase[b], endp = Cbase[b + 1];

    lcnt[tid] = 0; lcnt[tid + 256] = 0;
    __syncthreads();
    for (int k = base + tid; k < endp; k += 256)
        atomicAdd(&lcnt[(ebuf[k] >> 16) - row0], 1);
    __syncthreads();

    int c0 = lcnt[2 * tid], c1 = lcnt[2 * tid + 1];
    int ps = c0 + c1;
    int s = ps;
#pragma unroll
    for (int off = 1; off < 64; off <<= 1) {
        int u = __shfl_up(s, off, 64);
        if (l >= off) s += u;
    }
    if (l == 63) ws[w] = s;
    __syncthreads();
    int woff = 0;
    for (int k = 0; k < w; ++k) woff += ws[k];
    int excl = woff + s - ps;                      // pair-exclusive prefix
    if (2 * tid < nr)     rowptr[row0 + 2 * tid]     = base + excl;
    if (2 * tid + 1 < nr) rowptr[row0 + 2 * tid + 1] = base + excl + c0;
    lcur[2 * tid] = excl;
    lcur[2 * tid + 1] = excl + c0;
    __syncthreads();

    for (int k = base + tid; k < endp; k += 256) {
        unsigned rec = ebuf[k];
        int r = (rec >> 16) - row0, c = rec & 0xFFFF;
        int rel = atomicAdd(&lcur[r], 1);
        ecol[base + rel] = c;
    }
}

// ---------------------------------------------------------------------------
// Fused sparse attention, one wave per node, depth-4 KV pipeline with a
// clamped column ring. Launched in 4 slices for profiling visibility.
// ---------------------------------------------------------------------------
__global__ __launch_bounds__(256) void attn_fused(
    const unsigned short* __restrict__ QKV,
    const int* __restrict__ rowptr, const int* __restrict__ ecol,
    unsigned short* __restrict__ attn_t, int i0, int i1) {
    int i = i0 + blockIdx.x * 4 + (threadIdx.x >> 6);
    if (i >= i1) return;
    int l = threadIdx.x & 63;

    ushort4 q4 = *reinterpret_cast<const ushort4*>(QKV + (size_t)i * 768 + l * 4);
    float q0 = bf2f(q4.x), q1 = bf2f(q4.y), q2 = bf2f(q4.z), q3 = bf2f(q4.w);

    int j = rowptr[i], end = rowptr[i + 1];
    float z = 0.f, a0 = 0.f, a1 = 0.f, a2 = 0.f, a3 = 0.f;

    if (j < end) {
        int last = end - 1;
#define CL(jj) ecol[(jj) < last ? (jj) : last]
#define KVL(c) (*reinterpret_cast<const u16x8*>(QKV + (size_t)(c) * 768 + 256 + l * 8))
        int cA = CL(j), cB = CL(j + 1), cC = CL(j + 2), cD = CL(j + 3);
        u16x8 kvA = KVL(cA), kvB = KVL(cB), kvC = KVL(cC), kvD = KVL(cD);
        int r0 = CL(j + 4), r1 = CL(j + 5), r2 = CL(j + 6), r3 = CL(j + 7);

#define STEP(KV) { \
        float s = q0 * bf2f(KV[0]) + q1 * bf2f(KV[1]) + q2 * bf2f(KV[2]) + q3 * bf2f(KV[3]); \
        s += __shfl_xor(s, 1, 64); \
        s += __shfl_xor(s, 2, 64); \
        s += __shfl_xor(s, 4, 64); \
        float wgt = __expf(s); \
        z += wgt; \
        a0 += wgt * bf2f(KV[4]); a1 += wgt * bf2f(KV[5]); \
        a2 += wgt * bf2f(KV[6]); a3 += wgt * bf2f(KV[7]); \
        KV = KVL(r0); r0 = r1; r1 = r2; r2 = r3; r3 = CL(j + 8); \
        ++j; }

        while (j < end) {
            STEP(kvA);
            if (j < end) STEP(kvB);
            if (j < end) STEP(kvC);
            if (j < end) STEP(kvD);
        }
#undef STEP
#undef KVL
#undef CL
    }

    float inv = (z > 0.f) ? 1.0f / z : 0.f;
    ushort4 o;
    o.x = f2bf(a0 * inv); o.y = f2bf(a1 * inv);
    o.z = f2bf(a2 * inv); o.w = f2bf(a3 * inv);
    int R = i >> 7, row = i & 127;
    int ks = l >> 4, kb = (l & 15) >> 1, j4 = (l & 1) * 4;
    *reinterpret_cast<ushort4*>(attn_t + (size_t)R * 32768 + ks * 8192 + kb * 1024 + row * 8 + j4) = o;
}

// ---------------------------------------------------------------------------
// Launch
// ---------------------------------------------------------------------------
extern "C" void kernel_launch(void* const* d_in, const int* in_sizes, int n_in,
                              void* d_out, int out_size, void* d_ws, size_t ws_size,
                              hipStream_t stream) {
    const float* x  = (const float*)d_in[0];
    const int*   row = (const int*)d_in[1];
    const int*   col = (const int*)d_in[2];
    const float* Wq = (const float*)d_in[3];
    const float* bq = (const float*)d_in[4];
    const float* Wk = (const float*)d_in[5];
    const float* bk = (const float*)d_in[6];
    const float* Wv = (const float*)d_in[7];
    const float* bv = (const float*)d_in[8];
    const float* Wo = (const float*)d_in[9];
    const float* bo = (const float*)d_in[10];
    int N = in_sizes[0] / DIM;
    int E = in_sizes[1];
    float* out = (float*)d_out;

    int Rtiles = (N + 127) / 128;
    int NB = (N + 511) >> 9;                       // coarse buckets (98)
    int nblk = (E + EPB - 1) / EPB;                // multisplit blocks (391)

    char* p = (char*)d_ws;
    auto alloc = [&](size_t bytes) {
        char* r = p;
        p += (bytes + 255) & ~(size_t)255;
        return r;
    };
    unsigned short* xt     = (unsigned short*)alloc((size_t)Rtiles * 32768 * 2);
    unsigned short* QKV    = (unsigned short*)alloc((size_t)N * 768 * 2);
    unsigned short* attn_t = (unsigned short*)alloc((size_t)Rtiles * 32768 * 2);
    unsigned short* WqkvT  = (unsigned short*)alloc((size_t)768 * DIM * 2);
    unsigned short* WoT    = (unsigned short*)alloc((size_t)DIM * DIM * 2);
    float* bqkv = (float*)alloc(768 * sizeof(float));
    int* rowptr = (int*)alloc((size_t)(N + 1) * sizeof(int));
    int* H      = (int*)alloc((size_t)NB * nblk * sizeof(int));
    int* Tb     = (int*)alloc((size_t)NB * sizeof(int));
    int* Cbase  = (int*)alloc((size_t)(NB + 1) * sizeof(int));
    unsigned* ebuf = (unsigned*)alloc((size_t)E * sizeof(unsigned));
    int* ecol   = (int*)alloc((size_t)E * sizeof(int));

    // fused prep: weights + biases + x conversion
    int prep_items = PREP_W0 + N * 32;
    prep_fused<<<(prep_items + 255) / 256, 256, 0, stream>>>(
        Wq, Wk, Wv, Wo, bq, bk, bv, x, WqkvT, WoT, bqkv, xt, N);

    // multisplit-derived CSR
    hist_coarse<<<nblk, 256, 0, stream>>>(row, H, E, nblk, NB);
    bucket_totals<<<NB, 256, 0, stream>>>(H, Tb, nblk);
    scan_buckets<<<1, 64, 0, stream>>>(Tb, Cbase, NB, rowptr, N);
    scan_coarse<<<NB, 64, 0, stream>>>(H, Cbase, nblk);
    scatter_coarse<<<nblk, 256, 0, stream>>>(row, col, H, ebuf, E, nblk, NB);
    fine_fused<<<NB, 256, 0, stream>>>(ebuf, Cbase, rowptr, ecol, N);

    // fused QKV projection -> bf16 records [N][768]  (XCD-swizzled)
    gemm_tiled<1, 6><<<Rtiles * 6, 256, 0, stream>>>(xt, WqkvT, bqkv, QKV, N, 768);

    // fused sparse attention in 4 slices (per-dispatch profiling visibility)
    int q4n = (N + 3) / 4;
    for (int s4 = 0; s4 < 4; ++s4) {
        int i0 = s4 * q4n;
        int i1 = (s4 == 3) ? N : (s4 + 1) * q4n;
        if (i0 >= i1) continue;
        attn_fused<<<(i1 - i0 + 3) / 4, 256, 0, stream>>>(QKV, rowptr, ecol, attn_t, i0, i1);
    }

    // output projection -> f32 out  (XCD-swizzled)
    gemm_tiled<0, 2><<<Rtiles * 2, 256, 0, stream>>>(attn_t, WoT, bo, out, N, DIM);
}

// Round 10
// 395.075 us; speedup vs baseline: 3.0091x; 1.0542x over previous
//
#include <hip/hip_runtime.h>
#include <hip/hip_bf16.h>

#define DIM 256
#define NH 8

typedef __attribute__((ext_vector_type(4))) float f32x4;
typedef __attribute__((ext_vector_type(8))) short bf16x8;
typedef __attribute__((ext_vector_type(8))) unsigned short u16x8;

__device__ __forceinline__ float bf2f(unsigned short u) {
    union { unsigned int i; float f; } x; x.i = ((unsigned int)u) << 16; return x.f;
}
__device__ __forceinline__ unsigned short f2bf(float f) {
    union { float f; unsigned int i; } x; x.f = f;
    unsigned int r = x.i + 0x7fffu + ((x.i >> 16) & 1u);
    return (unsigned short)(r >> 16);
}

// ---------------------------------------------------------------------------
// Layouts.
// QKV record per node (768 bf16): [0..255]=Q head-contig, [256..767]=KV
// lane-interleaved (lane l owns {k[4l..4l+3], v[4l..4l+3]} = 16B).
// Tiled GEMM operand layout: off(R,ks,kb,row,j)=R*32768+ks*8192+kb*1024+row*8+j
// == the LDS layout: staging is a contiguous copy; ds_read_b128 conflict-free.
// Edge sort: coarse buckets of 512 rows; packed edge record = (row<<16)|col.
// GEMM epilogue: LDS round-trip (XOR-16B swizzle) -> dwordx4 global stores.
// ---------------------------------------------------------------------------
__device__ __forceinline__ void map_col(int o, int& which, int& c) {
    int cp;
    if (o < 256) { which = 0; cp = o; }
    else {
        int u = o - 256;
        int lane = u >> 3, slot = u & 7;
        which = (slot < 4) ? 1 : 2;
        cp = lane * 4 + (slot & 3);
    }
    c = (cp & 31) * 8 + (cp >> 5);   // reference reshape: c = d*NH + h
}

// Fused prep: WqkvT (tiled), WoT (tiled), bqkv, and x -> tiled bf16.
#define PREP_W0 262912
__global__ void prep_fused(const float* __restrict__ Wq, const float* __restrict__ Wk,
                           const float* __restrict__ Wv, const float* __restrict__ Wo,
                           const float* __restrict__ bq, const float* __restrict__ bk,
                           const float* __restrict__ bv, const float* __restrict__ x,
                           unsigned short* __restrict__ WqkvT,
                           unsigned short* __restrict__ WoT,
                           float* __restrict__ bqkv,
                           unsigned short* __restrict__ xt, int M) {
    int idx = blockIdx.x * 256 + threadIdx.x;
    if (idx < 768 * 256) {
        int CB = idx >> 15;
        int rem = idx & 32767;
        int ks = rem >> 13, kb = (rem >> 10) & 7, ci = (rem >> 3) & 127, jj = rem & 7;
        int o = CB * 128 + ci;
        int k = ks * 64 + kb * 8 + jj;
        int which, c; map_col(o, which, c);
        const float* W = (which == 0) ? Wq : (which == 1 ? Wk : Wv);
        float scale = (which == 0) ? 0.17677669529663687f : 1.0f;
        WqkvT[idx] = f2bf(W[k * DIM + c] * scale);
    } else if (idx < 768 * 256 + 256 * 256) {
        int id2 = idx - 768 * 256;
        int CB = id2 >> 15;
        int rem = id2 & 32767;
        int ks = rem >> 13, kb = (rem >> 10) & 7, ci = (rem >> 3) & 127, jj = rem & 7;
        int o = CB * 128 + ci;
        int cp = ks * 64 + kb * 8 + jj;
        WoT[id2] = f2bf(Wo[((cp & 31) * 8 + (cp >> 5)) * DIM + o]);
    } else if (idx < PREP_W0) {
        int o = idx - (768 * 256 + 256 * 256);
        if (o < 768) {
            int which, c; map_col(o, which, c);
            const float* b = (which == 0) ? bq : (which == 1 ? bk : bv);
            float scale = (which == 0) ? 0.17677669529663687f : 1.0f;
            bqkv[o] = b[c] * scale;
        }
    } else {
        int t = idx - PREP_W0;
        int r = t >> 5;
        if (r >= M) return;
        int kc = (t & 31) * 8;
        float4 v0 = *reinterpret_cast<const float4*>(x + (size_t)r * DIM + kc);
        float4 v1 = *reinterpret_cast<const float4*>(x + (size_t)r * DIM + kc + 4);
        u16x8 o;
        o[0] = f2bf(v0.x); o[1] = f2bf(v0.y); o[2] = f2bf(v0.z); o[3] = f2bf(v0.w);
        o[4] = f2bf(v1.x); o[5] = f2bf(v1.y); o[6] = f2bf(v1.z); o[7] = f2bf(v1.w);
        int R = r >> 7, row = r & 127, ks = kc >> 6, kb = (kc & 63) >> 3;
        *reinterpret_cast<u16x8*>(xt + (size_t)R * 32768 + ks * 8192 + kb * 1024 + row * 8) = o;
    }
}

// ---------------------------------------------------------------------------
// LDS-staged MFMA GEMM. 128x128 tile, 4 waves, BK=64, 32KB LDS.
// Bijective XCD swizzle; LDS-round-trip vectorized epilogue.
// ---------------------------------------------------------------------------
#define GLOAD_LDS16(gp, lp) \
    __builtin_amdgcn_global_load_lds( \
        (const __attribute__((address_space(1))) unsigned int*)(gp), \
        (__attribute__((address_space(3))) unsigned int*)(lp), 16, 0, 0)

template<int OUT_BF16, int CT>
__global__ __launch_bounds__(256) void gemm_tiled(
    const unsigned short* __restrict__ At, const unsigned short* __restrict__ Bt,
    const float* __restrict__ bias, void* __restrict__ Cout, int M, int ldc) {
    __shared__ unsigned short lds[16384];          // 32KB: A 16KB @0, B 16KB @8192
    int tid = threadIdx.x;
    int l = tid & 63, w = tid >> 6;

    // bijective XCD swizzle: orig%8 = physical XCD (round-robin dispatch)
    int nwg = gridDim.x;
    int q = nwg >> 3, r8 = nwg & 7;
    int xcd = blockIdx.x & 7, pos = blockIdx.x >> 3;
    int wg = (xcd < r8 ? xcd * (q + 1) : r8 * (q + 1) + (xcd - r8) * q) + pos;
    int xtile = wg / CT, ctile = wg % CT;

    const unsigned short* Abase = At + (size_t)xtile * 32768;
    const unsigned short* Bbase = Bt + (size_t)ctile * 32768;

    int rbase = (w >> 1) * 64 + (l & 15);
    int cbase = (w & 1) * 64 + (l & 15);
    int kq = l >> 4;

    f32x4 acc[4][4] = {};
#pragma unroll
    for (int ks = 0; ks < 4; ++ks) {
        if (ks) __syncthreads();
#pragma unroll
        for (int i = 0; i < 4; ++i) {
            GLOAD_LDS16(Abase + (size_t)ks * 8192 + i * 2048 + tid * 8, &lds[i * 2048 + tid * 8]);
            GLOAD_LDS16(Bbase + (size_t)ks * 8192 + i * 2048 + tid * 8, &lds[8192 + i * 2048 + tid * 8]);
        }
        __syncthreads();
#pragma unroll
        for (int kk = 0; kk < 2; ++kk) {
            int kb = kk * 4 + kq;
            bf16x8 a[4], b[4];
#pragma unroll
            for (int m = 0; m < 4; ++m)
                a[m] = *reinterpret_cast<const bf16x8*>(&lds[kb * 1024 + (rbase + m * 16) * 8]);
#pragma unroll
            for (int n = 0; n < 4; ++n)
                b[n] = *reinterpret_cast<const bf16x8*>(&lds[8192 + kb * 1024 + (cbase + n * 16) * 8]);
#pragma unroll
            for (int m = 0; m < 4; ++m)
#pragma unroll
                for (int n = 0; n < 4; ++n)
                    acc[m][n] = __builtin_amdgcn_mfma_f32_16x16x32_bf16(a[m], b[n], acc[m][n], 0, 0, 0);
        }
    }

    // ---- epilogue: LDS round-trip -> vectorized stores ----
    int rb = (l >> 4) * 4, cc = l & 15;
    char* lc = (char*)lds;

    if (OUT_BF16) {
        // 128x128 bf16 tile = 32KB, one pass. 16B-chunk XOR swizzle by row&7.
        __syncthreads();                           // all LDS reads of K-loop done
#pragma unroll
        for (int n = 0; n < 4; ++n) {
            int c_blk = (w & 1) * 64 + n * 16 + cc;
            float bv = bias[ctile * 128 + c_blk];
#pragma unroll
            for (int m = 0; m < 4; ++m) {
#pragma unroll
                for (int j = 0; j < 4; ++j) {
                    int r_blk = (w >> 1) * 64 + m * 16 + rb + j;
                    int byte = r_blk * 256 + ((((c_blk * 2) >> 4) ^ (r_blk & 7)) << 4) + ((c_blk * 2) & 15);
                    *reinterpret_cast<unsigned short*>(lc + byte) = f2bf(acc[m][n][j] + bv);
                }
            }
        }
        __syncthreads();
        int r2 = tid >> 1;
        int gr = xtile * 128 + r2;
#pragma unroll
        for (int i = 0; i < 8; ++i) {
            int ch = (tid & 1) * 8 + i;
            uint4 v = *reinterpret_cast<uint4*>(lc + r2 * 256 + ((ch ^ (r2 & 7)) << 4));
            if (gr < M)
                *reinterpret_cast<uint4*>((unsigned short*)Cout + (size_t)gr * ldc + ctile * 128 + ch * 8) = v;
        }
    } else {
        // f32: two 32KB passes (rows 0-63 by waves 0,1; rows 64-127 by 2,3).
#pragma unroll
        for (int p = 0; p < 2; ++p) {
            __syncthreads();
            if ((w >> 1) == p) {
#pragma unroll
                for (int n = 0; n < 4; ++n) {
                    int c_blk = (w & 1) * 64 + n * 16 + cc;
                    float bv = bias[ctile * 128 + c_blk];
#pragma unroll
                    for (int m = 0; m < 4; ++m) {
#pragma unroll
                        for (int j = 0; j < 4; ++j) {
                            int rl = m * 16 + rb + j;           // 0..63
                            int byte = rl * 512 + ((((c_blk * 4) >> 4) ^ (rl & 7)) << 4) + ((c_blk * 4) & 15);
                            *reinterpret_cast<float*>(lc + byte) = acc[m][n][j] + bv;
                        }
                    }
                }
            }
            __syncthreads();
            int rl = tid >> 2;
            int gr = xtile * 128 + p * 64 + rl;
#pragma unroll
            for (int i = 0; i < 8; ++i) {
                int ch = (tid & 3) * 8 + i;
                uint4 v = *reinterpret_cast<uint4*>(lc + rl * 512 + ((ch ^ (rl & 7)) << 4));
                if (gr < M)
                    *reinterpret_cast<uint4*>((float*)Cout + (size_t)gr * ldc + ctile * 128 + ch * 4) = v;
            }
        }
    }
}

// ---------------------------------------------------------------------------
// Edge multisplit + CSR, all derived from per-block coarse histograms.
// ---------------------------------------------------------------------------
#define EPB 4096
#define NBMAX 128

__global__ __launch_bounds__(256) void hist_coarse(const int* __restrict__ row,
                                                   int* __restrict__ H, int E, int nblk, int NB) {
    __shared__ int h[NBMAX];
    int tid = threadIdx.x, blk = blockIdx.x;
    for (int b = tid; b < NB; b += 256) h[b] = 0;
    __syncthreads();
    int base = blk * EPB;
    int nloc = min(EPB, E - base);
    for (int k = tid; k < nloc; k += 256) atomicAdd(&h[row[base + k] >> 9], 1);
    __syncthreads();
    for (int b = tid; b < NB; b += 256) H[b * nblk + blk] = h[b];
}

__global__ __launch_bounds__(256) void bucket_totals(const int* __restrict__ H,
                                                     int* __restrict__ Tb, int nblk) {
    __shared__ int ws[4];
    int b = blockIdx.x, tid = threadIdx.x;
    int s = 0;
    for (int k = tid; k < nblk; k += 256) s += H[b * nblk + k];
#pragma unroll
    for (int off = 1; off < 64; off <<= 1) s += __shfl_xor(s, off, 64);
    if ((tid & 63) == 0) ws[tid >> 6] = s;
    __syncthreads();
    if (tid == 0) Tb[b] = ws[0] + ws[1] + ws[2] + ws[3];
}

__global__ void scan_buckets(const int* __restrict__ Tb, int* __restrict__ Cbase,
                             int NB, int* __restrict__ rowptr, int N) {
    int l = threadIdx.x;
    int carry = 0;
    for (int base = 0; base < NB; base += 64) {
        int idx = base + l;
        int v = (idx < NB) ? Tb[idx] : 0;
        int s = v;
#pragma unroll
        for (int off = 1; off < 64; off <<= 1) {
            int u = __shfl_up(s, off, 64);
            if (l >= off) s += u;
        }
        if (idx < NB) Cbase[idx] = s - v + carry;
        carry += __shfl(s, 63, 64);
    }
    if (l == 0) { Cbase[NB] = carry; rowptr[N] = carry; }
}

__global__ void scan_coarse(int* __restrict__ H, const int* __restrict__ Cbase, int nblk) {
    int b = blockIdx.x, l = threadIdx.x;
    int carry = Cbase[b];
    for (int s0 = 0; s0 < nblk; s0 += 64) {
        int idx = s0 + l;
        int v = (idx < nblk) ? H[b * nblk + idx] : 0;
        int s = v;
#pragma unroll
        for (int off = 1; off < 64; off <<= 1) {
            int u = __shfl_up(s, off, 64);
            if (l >= off) s += u;
        }
        if (idx < nblk) H[b * nblk + idx] = s - v + carry;
        carry += __shfl(s, 63, 64);
    }
}

__global__ __launch_bounds__(256) void scatter_coarse(const int* __restrict__ row,
                                                      const int* __restrict__ col,
                                                      const int* __restrict__ H,
                                                      unsigned* __restrict__ ebuf,
                                                      int E, int nblk, int NB) {
    __shared__ int h[NBMAX];
    __shared__ int lofs[NBMAX + 1];
    __shared__ int dstv[NBMAX];
    __shared__ unsigned rin[EPB];
    __shared__ unsigned rsort[EPB];
    int tid = threadIdx.x, blk = blockIdx.x;
    int base = blk * EPB;
    int nloc = min(EPB, E - base);

    for (int b = tid; b < NB; b += 256) h[b] = 0;
    __syncthreads();
    for (int k = tid; k < nloc; k += 256) {
        int r = row[base + k], c = col[base + k];
        rin[k] = ((unsigned)r << 16) | (unsigned)c;
        atomicAdd(&h[r >> 9], 1);
    }
    __syncthreads();
    if (tid == 0) {
        int run = 0;
        for (int b = 0; b < NB; ++b) { lofs[b] = run; run += h[b]; }
        lofs[NB] = run;
    }
    __syncthreads();
    for (int b = tid; b < NB; b += 256) { h[b] = lofs[b]; dstv[b] = H[b * nblk + blk]; }
    __syncthreads();
    for (int k = tid; k < nloc; k += 256) {
        unsigned rec = rin[k];
        int pos = atomicAdd(&h[rec >> 25], 1);
        rsort[pos] = rec;
    }
    __syncthreads();
    for (int b = 0; b < NB; ++b) {
        int o = lofs[b], cntb = lofs[b + 1] - o, dst = dstv[b];
        for (int k = tid; k < cntb; k += 256) ebuf[dst + k] = rsort[o + k];
    }
}

__global__ __launch_bounds__(256) void fine_fused(const unsigned* __restrict__ ebuf,
                                                  const int* __restrict__ Cbase,
                                                  int* __restrict__ rowptr,
                                                  int* __restrict__ ecol, int N) {
    __shared__ int lcnt[512];
    __shared__ int lcur[512];
    __shared__ int ws[4];
    int b = blockIdx.x, tid = threadIdx.x, l = tid & 63, w = tid >> 6;
    int row0 = b << 9;
    int nr = min(512, N - row0);
    int base = Cbase[b], endp = Cbase[b + 1];

    lcnt[tid] = 0; lcnt[tid + 256] = 0;
    __syncthreads();
    for (int k = base + tid; k < endp; k += 256)
        atomicAdd(&lcnt[(ebuf[k] >> 16) - row0], 1);
    __syncthreads();

    int c0 = lcnt[2 * tid], c1 = lcnt[2 * tid + 1];
    int ps = c0 + c1;
    int s = ps;
#pragma unroll
    for (int off = 1; off < 64; off <<= 1) {
        int u = __shfl_up(s, off, 64);
        if (l >= off) s += u;
    }
    if (l == 63) ws[w] = s;
    __syncthreads();
    int woff = 0;
    for (int k = 0; k < w; ++k) woff += ws[k];
    int excl = woff + s - ps;
    if (2 * tid < nr)     rowptr[row0 + 2 * tid]     = base + excl;
    if (2 * tid + 1 < nr) rowptr[row0 + 2 * tid + 1] = base + excl + c0;
    lcur[2 * tid] = excl;
    lcur[2 * tid + 1] = excl + c0;
    __syncthreads();

    for (int k = base + tid; k < endp; k += 256) {
        unsigned rec = ebuf[k];
        int r = (rec >> 16) - row0, c = rec & 0xFFFF;
        int rel = atomicAdd(&lcur[r], 1);
        ecol[base + rel] = c;
    }
}

// ---------------------------------------------------------------------------
// Fused sparse attention, one wave per node, depth-4 KV pipeline with a
// clamped column ring. Single launch.
// ---------------------------------------------------------------------------
__global__ __launch_bounds__(256) void attn_fused(
    const unsigned short* __restrict__ QKV,
    const int* __restrict__ rowptr, const int* __restrict__ ecol,
    unsigned short* __restrict__ attn_t, int N) {
    int i = blockIdx.x * 4 + (threadIdx.x >> 6);
    if (i >= N) return;
    int l = threadIdx.x & 63;

    ushort4 q4 = *reinterpret_cast<const ushort4*>(QKV + (size_t)i * 768 + l * 4);
    float q0 = bf2f(q4.x), q1 = bf2f(q4.y), q2 = bf2f(q4.z), q3 = bf2f(q4.w);

    int j = rowptr[i], end = rowptr[i + 1];
    float z = 0.f, a0 = 0.f, a1 = 0.f, a2 = 0.f, a3 = 0.f;

    if (j < end) {
        int last = end - 1;
#define CL(jj) ecol[(jj) < last ? (jj) : last]
#define KVL(c) (*reinterpret_cast<const u16x8*>(QKV + (size_t)(c) * 768 + 256 + l * 8))
        int cA = CL(j), cB = CL(j + 1), cC = CL(j + 2), cD = CL(j + 3);
        u16x8 kvA = KVL(cA), kvB = KVL(cB), kvC = KVL(cC), kvD = KVL(cD);
        int r0 = CL(j + 4), r1 = CL(j + 5), r2 = CL(j + 6), r3 = CL(j + 7);

#define STEP(KV) { \
        float s = q0 * bf2f(KV[0]) + q1 * bf2f(KV[1]) + q2 * bf2f(KV[2]) + q3 * bf2f(KV[3]); \
        s += __shfl_xor(s, 1, 64); \
        s += __shfl_xor(s, 2, 64); \
        s += __shfl_xor(s, 4, 64); \
        float wgt = __expf(s); \
        z += wgt; \
        a0 += wgt * bf2f(KV[4]); a1 += wgt * bf2f(KV[5]); \
        a2 += wgt * bf2f(KV[6]); a3 += wgt * bf2f(KV[7]); \
        KV = KVL(r0); r0 = r1; r1 = r2; r2 = r3; r3 = CL(j + 8); \
        ++j; }

        while (j < end) {
            STEP(kvA);
            if (j < end) STEP(kvB);
            if (j < end) STEP(kvC);
            if (j < end) STEP(kvD);
        }
#undef STEP
#undef KVL
#undef CL
    }

    float inv = (z > 0.f) ? 1.0f / z : 0.f;
    ushort4 o;
    o.x = f2bf(a0 * inv); o.y = f2bf(a1 * inv);
    o.z = f2bf(a2 * inv); o.w = f2bf(a3 * inv);
    int R = i >> 7, row = i & 127;
    int ks = l >> 4, kb = (l & 15) >> 1, j4 = (l & 1) * 4;
    *reinterpret_cast<ushort4*>(attn_t + (size_t)R * 32768 + ks * 8192 + kb * 1024 + row * 8 + j4) = o;
}

// ---------------------------------------------------------------------------
// Launch
// ---------------------------------------------------------------------------
extern "C" void kernel_launch(void* const* d_in, const int* in_sizes, int n_in,
                              void* d_out, int out_size, void* d_ws, size_t ws_size,
                              hipStream_t stream) {
    const float* x  = (const float*)d_in[0];
    const int*   row = (const int*)d_in[1];
    const int*   col = (const int*)d_in[2];
    const float* Wq = (const float*)d_in[3];
    const float* bq = (const float*)d_in[4];
    const float* Wk = (const float*)d_in[5];
    const float* bk = (const float*)d_in[6];
    const float* Wv = (const float*)d_in[7];
    const float* bv = (const float*)d_in[8];
    const float* Wo = (const float*)d_in[9];
    const float* bo = (const float*)d_in[10];
    int N = in_sizes[0] / DIM;
    int E = in_sizes[1];
    float* out = (float*)d_out;

    int Rtiles = (N + 127) / 128;
    int NB = (N + 511) >> 9;                       // coarse buckets (98)
    int nblk = (E + EPB - 1) / EPB;                // multisplit blocks (391)

    char* p = (char*)d_ws;
    auto alloc = [&](size_t bytes) {
        char* r = p;
        p += (bytes + 255) & ~(size_t)255;
        return r;
    };
    unsigned short* xt     = (unsigned short*)alloc((size_t)Rtiles * 32768 * 2);
    unsigned short* QKV    = (unsigned short*)alloc((size_t)N * 768 * 2);
    unsigned short* attn_t = (unsigned short*)alloc((size_t)Rtiles * 32768 * 2);
    unsigned short* WqkvT  = (unsigned short*)alloc((size_t)768 * DIM * 2);
    unsigned short* WoT    = (unsigned short*)alloc((size_t)DIM * DIM * 2);
    float* bqkv = (float*)alloc(768 * sizeof(float));
    int* rowptr = (int*)alloc((size_t)(N + 1) * sizeof(int));
    int* H      = (int*)alloc((size_t)NB * nblk * sizeof(int));
    int* Tb     = (int*)alloc((size_t)NB * sizeof(int));
    int* Cbase  = (int*)alloc((size_t)(NB + 1) * sizeof(int));
    unsigned* ebuf = (unsigned*)alloc((size_t)E * sizeof(unsigned));
    int* ecol   = (int*)alloc((size_t)E * sizeof(int));

    // fused prep: weights + biases + x conversion
    int prep_items = PREP_W0 + N * 32;
    prep_fused<<<(prep_items + 255) / 256, 256, 0, stream>>>(
        Wq, Wk, Wv, Wo, bq, bk, bv, x, WqkvT, WoT, bqkv, xt, N);

    // multisplit-derived CSR
    hist_coarse<<<nblk, 256, 0, stream>>>(row, H, E, nblk, NB);
    bucket_totals<<<NB, 256, 0, stream>>>(H, Tb, nblk);
    scan_buckets<<<1, 64, 0, stream>>>(Tb, Cbase, NB, rowptr, N);
    scan_coarse<<<NB, 64, 0, stream>>>(H, Cbase, nblk);
    scatter_coarse<<<nblk, 256, 0, stream>>>(row, col, H, ebuf, E, nblk, NB);
    fine_fused<<<NB, 256, 0, stream>>>(ebuf, Cbase, rowptr, ecol, N);

    // fused QKV projection -> bf16 records [N][768]  (XCD-swizzled)
    gemm_tiled<1, 6><<<Rtiles * 6, 256, 0, stream>>>(xt, WqkvT, bqkv, QKV, N, 768);

    // fused sparse attention (single launch)
    attn_fused<<<(N + 3) / 4, 256, 0, stream>>>(QKV, rowptr, ecol, attn_t, N);

    // output projection -> f32 out  (XCD-swizzled)
    gemm_tiled<0, 2><<<Rtiles * 2, 256, 0, stream>>>(attn_t, WoT, bo, out, N, DIM);
}